// Round 5
// baseline (353.052 us; speedup 1.0000x reference)
//
#include <hip/hip_runtime.h>
#include <hip/hip_bf16.h>

#define HIDDEN   128
#define EDGE_DIM 32
#define NNODE    50000
#define NEDGE    800000
#define KSTEPS   9          // K = 288 = 9*32  (128 src + 128 dst + 32 edge_attr)
#define NFRAG    8          // 128 output cols / 16
#define LDS_KS   8          // K-steps staged in LDS (8*8KB = 65536 B, static max)
#define NGROUP   (NEDGE / 128)   // 6250 groups of 128 edges
#define GRID_MAIN 512            // 2 resident blocks per CU

typedef __attribute__((ext_vector_type(4))) float        f32x4;
typedef __attribute__((ext_vector_type(8))) short        bf16x8;
typedef __attribute__((ext_vector_type(4))) unsigned int u32x4;

#define BPACK_USHORTS  (KSTEPS * NFRAG * 64 * 8)   // 36864 bf16 = 73728 B
#define BIAS_OFF_BYTES (BPACK_USHORTS * 2)         // 73728
#define FLAG_OFF_BYTES (BIAS_OFF_BYTES + 128 * 4)  // 74240
#define NODE_OFF_BYTES 74752                       // 16B-aligned; bf16 nodes, 12.8 MB
#define IDX_OFF_BYTES  (NODE_OFF_BYTES + NNODE * HIDDEN * 2)   // 12874752
#define WS_NEEDED      (IDX_OFF_BYTES + 2 * NEDGE * 4)         // + 6.4 MB idx32
#define WS_NEEDED_FP32 0   // fallback needs only Bpack region

__device__ __forceinline__ unsigned short f2bf(float f) {
  unsigned u = __builtin_bit_cast(unsigned, f);
  u += 0x7FFFu + ((u >> 16) & 1u);   // RNE
  return (unsigned short)(u >> 16);
}

__device__ __forceinline__ unsigned cvt_pk_bf16(float a, float b) {
  union { __hip_bfloat162 h; unsigned u; } cv;
  cv.h = __float22bfloat162_rn(make_float2(a, b));   // v_cvt_pk_bf16_f32
  return cv.u;
}

__device__ __forceinline__ bf16x8 pack8(f32x4 lo, f32x4 hi) {
  u32x4 u;
  u[0] = cvt_pk_bf16(lo[0], lo[1]);
  u[1] = cvt_pk_bf16(lo[2], lo[3]);
  u[2] = cvt_pk_bf16(hi[0], hi[1]);
  u[3] = cvt_pk_bf16(hi[2], hi[3]);
  return __builtin_bit_cast(bf16x8, u);
}

// async global->LDS, 16B per lane, LDS dest = wave-uniform base + lane*16
__device__ __forceinline__ void gload_lds16(const void* g, void* l) {
  __builtin_amdgcn_global_load_lds(
      (const __attribute__((address_space(1))) unsigned int*)g,
      (__attribute__((address_space(3))) unsigned int*)l, 16, 0, 0);
}

#define MFMA(a, b, c) __builtin_amdgcn_mfma_f32_16x16x32_bf16((a), (b), (c), 0, 0, 0)

// ---- setup 1: folded, fragment-packed B (bf16) + effective bias + idx dtype flag
__global__ void setup_kernel(const float* __restrict__ W_edge,
                             const float* __restrict__ b_edge,
                             const float* __restrict__ W1,
                             const float* __restrict__ b1,
                             const void*  __restrict__ eidx,
                             unsigned short* __restrict__ Bpack,
                             float* __restrict__ bias_eff,
                             int*   __restrict__ flag64) {
  const int bid = blockIdx.x, tid = threadIdx.x;
  if (bid < 36) {
    const int pair  = bid * 2 + (tid >> 6);   // 0..71 = kstep*8 + nfrag
    const int lane  = tid & 63;
    const int kstep = pair >> 3;
    const int f     = pair & 7;
    const int col   = f * 16 + (lane & 15);
    const int kbase = kstep * 32 + (lane >> 4) * 8;
    float vals[8];
#pragma unroll
    for (int j = 0; j < 8; ++j) {
      const int k = kbase + j;
      float val;
      if (k < 128) {
        val = W1[k * 128 + col];
      } else if (k < 256) {
        val = W1[(k + 128) * 128 + col];
      } else {
        const int kk = k - 256;
        float s = 0.f;
        for (int t = 0; t < 128; ++t)
          s = fmaf(W_edge[kk * 128 + t], W1[(128 + t) * 128 + col], s);
        val = s;
      }
      vals[j] = val;
    }
    u32x4 sv;
#pragma unroll
    for (int j = 0; j < 4; ++j)
      sv[j] = (unsigned)f2bf(vals[2 * j]) | ((unsigned)f2bf(vals[2 * j + 1]) << 16);
    *(u32x4*)(Bpack + ((kstep * NFRAG + f) * 64 + lane) * 8) = sv;
  } else {
    if (tid < 128) {
      float s = b1[tid];
      for (int t = 0; t < 128; ++t)
        s = fmaf(b_edge[t], W1[(128 + t) * 128 + tid], s);
      bias_eff[tid] = s;
    }
    if (tid == 0) {
      const unsigned* w = (const unsigned*)eidx;
      int all0 = 1;
      for (int i = 0; i < 64; ++i) all0 &= (w[2 * i + 1] == 0u) ? 1 : 0;
      *flag64 = all0;
    }
  }
}

// ---- setup 2: node_features fp32 -> bf16 (row-major, same layout)
__global__ __launch_bounds__(256) void cvt_nodes_kernel(const float* __restrict__ nodef,
                                                        unsigned short* __restrict__ nbf) {
  const int i = blockIdx.x * 256 + threadIdx.x;   // one 8-elem chunk per thread
  if (i >= NNODE * HIDDEN / 8) return;
  f32x4 lo = *(const f32x4*)(nodef + i * 8);
  f32x4 hi = *(const f32x4*)(nodef + i * 8 + 4);
  *(bf16x8*)(nbf + i * 8) = pack8(lo, hi);
}

// ---- setup 3: edge_index (int64 or int32) -> int32 in ws
__global__ __launch_bounds__(256) void cvt_idx_kernel(const void* __restrict__ eidx,
                                                      const int* __restrict__ flag64,
                                                      int* __restrict__ idx32) {
  const int i = blockIdx.x * 256 + threadIdx.x;
  if (i >= 2 * NEDGE) return;
  if (*flag64) idx32[i] = (int)((const long long*)eidx)[i];
  else         idx32[i] = ((const int*)eidx)[i];
}

// ---- main: persistent blocks. 256 thr = 4 waves, 32 edges/wave, grid-stride
// over groups. B staged ONCE per block; group loop is barrier-free with
// depth-2 idx prefetch and register-rotated src-gather prefetch.
__global__ __launch_bounds__(256, 2) void edge_attn_kernel(
    const unsigned short* __restrict__ nbf,
    const float* __restrict__ eattr,
    const int*   __restrict__ idx32,
    const unsigned short* __restrict__ Bpack,
    const float* __restrict__ bias_eff,
    const float* __restrict__ W2,
    const float* __restrict__ b2,
    float* __restrict__ out) {
  __shared__ unsigned short lds_b[LDS_KS * NFRAG * 64 * 8];   // 65536 B

  const int tid  = threadIdx.x;
  const int lane = tid & 63;
  const int wid  = tid >> 6;                 // 0..3
  const int l15  = lane & 15;
  const int kg   = lane >> 4;                // 0..3
  const int lofs = wid * 32 + l15;

  // stage B ks0..7 into LDS once (async, drained by the single barrier)
#pragma unroll
  for (int i = 0; i < 16; ++i) {
    const char* g = (const char*)Bpack + (size_t)(i * 256 + tid) * 16;
    char*       l = (char*)lds_b + (size_t)(i * 256 + wid * 64) * 16;
    gload_lds16(g, l);
  }

  // persistent registers: ks8 B-frags, W2, bias
  bf16x8 bfr8[NFRAG];
#pragma unroll
  for (int f = 0; f < NFRAG; ++f)
    bfr8[f] = *(const bf16x8*)(Bpack + ((8 * NFRAG + f) * 64 + lane) * 8);
  float w2v[NFRAG], bv[NFRAG];
#pragma unroll
  for (int f = 0; f < NFRAG; ++f) {
    w2v[f] = W2[f * 16 + l15];
    bv[f]  = bias_eff[f * 16 + l15];
  }
  const float bias2 = b2[0];

  __syncthreads();   // the only barrier

  // ---- prologue: idx for first two groups + src gathers for first group
  int g  = blockIdx.x;
  int eA = g * 128 + lofs;
  int rA0 = idx32[eA],         rA1 = idx32[eA + 16];
  int cA0 = idx32[NEDGE + eA], cA1 = idx32[NEDGE + eA + 16];

  int gB = g + GRID_MAIN; if (gB >= NGROUP) gB = g;
  int eB = gB * 128 + lofs;
  int rB0 = idx32[eB],         rB1 = idx32[eB + 16];
  int cB0 = idx32[NEDGE + eB], cB1 = idx32[NEDGE + eB + 16];

  bf16x8 as0[4], as1[4];
#pragma unroll
  for (int ks = 0; ks < 4; ++ks) {
    as0[ks] = *(const bf16x8*)(nbf + (size_t)rA0 * HIDDEN + kg * 8 + ks * 32);
    as1[ks] = *(const bf16x8*)(nbf + (size_t)rA1 * HIDDEN + kg * 8 + ks * 32);
  }

#pragma unroll 1
  for (; g < NGROUP; g += GRID_MAIN) {
    // idx prefetch, 2 groups ahead (values consumed next iteration)
    int gC = g + 2 * GRID_MAIN; if (gC >= NGROUP) gC = g;
    const int eC = gC * 128 + lofs;
    const int rC0 = idx32[eC],         rC1 = idx32[eC + 16];
    const int cC0 = idx32[NEDGE + eC], cC1 = idx32[NEDGE + eC + 16];

    // dst gathers for current group (L2/L3)
    bf16x8 ad0[4], ad1[4];
#pragma unroll
    for (int ks = 0; ks < 4; ++ks) {
      ad0[ks] = *(const bf16x8*)(nbf + (size_t)cA0 * HIDDEN + kg * 8 + ks * 32);
      ad1[ks] = *(const bf16x8*)(nbf + (size_t)cA1 * HIDDEN + kg * 8 + ks * 32);
    }

    // eattr for current group (HBM stream; used at phase 3)
    const int e0 = g * 128 + lofs;
    const float* pe0 = eattr + (size_t)e0 * EDGE_DIM + kg * 8;
    const float* pe1 = pe0 + 16 * EDGE_DIM;
    f32x4 ea0lo = *(const f32x4*)(pe0);
    f32x4 ea0hi = *(const f32x4*)(pe0 + 4);
    f32x4 ea1lo = *(const f32x4*)(pe1);
    f32x4 ea1hi = *(const f32x4*)(pe1 + 4);

    // acc init with folded bias
    f32x4 acc[2][NFRAG];
#pragma unroll
    for (int m = 0; m < 2; ++m)
#pragma unroll
      for (int f = 0; f < NFRAG; ++f)
        acc[m][f] = (f32x4){bv[f], bv[f], bv[f], bv[f]};

    // phase 1: src rows, ks 0..3 (B from LDS)
#pragma unroll
    for (int ks = 0; ks < 4; ++ks)
#pragma unroll
      for (int f = 0; f < NFRAG; ++f) {
        bf16x8 bfr = *(const bf16x8*)(lds_b + ((ks * NFRAG + f) * 64 + lane) * 8);
        acc[0][f] = MFMA(as0[ks], bfr, acc[0][f]);
        acc[1][f] = MFMA(as1[ks], bfr, acc[1][f]);
      }

    // src gathers for NEXT group into the just-freed as regs
#pragma unroll
    for (int ks = 0; ks < 4; ++ks) {
      as0[ks] = *(const bf16x8*)(nbf + (size_t)rB0 * HIDDEN + kg * 8 + ks * 32);
      as1[ks] = *(const bf16x8*)(nbf + (size_t)rB1 * HIDDEN + kg * 8 + ks * 32);
    }

    // phase 2: dst rows, ks 4..7 (B from LDS)
#pragma unroll
    for (int ks = 0; ks < 4; ++ks)
#pragma unroll
      for (int f = 0; f < NFRAG; ++f) {
        bf16x8 bfr = *(const bf16x8*)(lds_b + (((ks + 4) * NFRAG + f) * 64 + lane) * 8);
        acc[0][f] = MFMA(ad0[ks], bfr, acc[0][f]);
        acc[1][f] = MFMA(ad1[ks], bfr, acc[1][f]);
      }

    // phase 3: edge_attr, ks 8 (B from persistent regs)
    {
      bf16x8 ae0 = pack8(ea0lo, ea0hi);
      bf16x8 ae1 = pack8(ea1lo, ea1hi);
#pragma unroll
      for (int f = 0; f < NFRAG; ++f) {
        acc[0][f] = MFMA(ae0, bfr8[f], acc[0][f]);
        acc[1][f] = MFMA(ae1, bfr8[f], acc[1][f]);
      }
    }

    // epilogue: ReLU + dot(W2), 16-lane xor-reduce, sigmoid, store
    float part[2][4];
#pragma unroll
    for (int m = 0; m < 2; ++m)
#pragma unroll
      for (int r = 0; r < 4; ++r) {
        float s = 0.f;
#pragma unroll
        for (int f = 0; f < NFRAG; ++f) {
          float h = fmaxf(acc[m][f][r], 0.f);
          s = fmaf(h, w2v[f], s);
        }
        part[m][r] = s;
      }
#pragma unroll
    for (int mask = 1; mask < 16; mask <<= 1)
#pragma unroll
      for (int m = 0; m < 2; ++m)
#pragma unroll
        for (int r = 0; r < 4; ++r)
          part[m][r] += __shfl_xor(part[m][r], mask, 64);

    if (l15 == 0) {
      const int obase = g * 128 + wid * 32;
#pragma unroll
      for (int m = 0; m < 2; ++m)
#pragma unroll
        for (int r = 0; r < 4; ++r) {
          float x = part[m][r] + bias2;
          out[obase + m * 16 + kg * 4 + r] = 1.f / (1.f + __expf(-x));
        }
    }

    // rotate idx pipeline
    rA0 = rB0; rA1 = rB1; cA0 = cB0; cA1 = cB1;
    rB0 = rC0; rB1 = rC1; cB0 = cC0; cB1 = cC1;
  }
}

// ---- fallback main (round-1 style, fp32 gathers) in case ws is too small
__global__ __launch_bounds__(256) void edge_attn_kernel_fp32(
    const float* __restrict__ nodef,
    const float* __restrict__ eattr,
    const void*  __restrict__ eidx,
    const unsigned short* __restrict__ Bpack,
    const float* __restrict__ bias_eff,
    const float* __restrict__ W2,
    const float* __restrict__ b2,
    const int*   __restrict__ flag64,
    float* __restrict__ out) {
  const int lane  = threadIdx.x & 63;
  const int wid   = threadIdx.x >> 6;
  const int ebase = blockIdx.x * 128 + wid * 32;
  const int l15   = lane & 15;
  const int kg    = lane >> 4;
  const int koff  = kg * 8;
  const int e0 = ebase + l15;
  const int e1 = e0 + 16;

  long r0, c0, r1, c1;
  if (*flag64) {
    const long long* p = (const long long*)eidx;
    r0 = (long)p[e0];          r1 = (long)p[e1];
    c0 = (long)p[NEDGE + e0];  c1 = (long)p[NEDGE + e1];
  } else {
    const int* p = (const int*)eidx;
    r0 = p[e0];          r1 = p[e1];
    c0 = p[NEDGE + e0];  c1 = p[NEDGE + e1];
  }

  f32x4 acc[2][NFRAG];
#pragma unroll
  for (int m = 0; m < 2; ++m)
#pragma unroll
    for (int f = 0; f < NFRAG; ++f)
      acc[m][f] = (f32x4){0.f, 0.f, 0.f, 0.f};

#pragma unroll 1
  for (int ks = 0; ks < KSTEPS; ++ks) {
    const float *p0, *p1;
    if (ks < 4)      { p0 = nodef + r0 * HIDDEN + ks * 32;       p1 = nodef + r1 * HIDDEN + ks * 32; }
    else if (ks < 8) { p0 = nodef + c0 * HIDDEN + (ks - 4) * 32; p1 = nodef + c1 * HIDDEN + (ks - 4) * 32; }
    else             { p0 = eattr + (long)e0 * EDGE_DIM;         p1 = eattr + (long)e1 * EDGE_DIM; }

    f32x4 lo0 = *(const f32x4*)(p0 + koff);
    f32x4 hi0 = *(const f32x4*)(p0 + koff + 4);
    f32x4 lo1 = *(const f32x4*)(p1 + koff);
    f32x4 hi1 = *(const f32x4*)(p1 + koff + 4);
    bf16x8 a0 = pack8(lo0, hi0);
    bf16x8 a1 = pack8(lo1, hi1);

#pragma unroll
    for (int f = 0; f < NFRAG; ++f) {
      bf16x8 bfr = *(const bf16x8*)(Bpack + ((ks * NFRAG + f) * 64 + lane) * 8);
      acc[0][f] = MFMA(a0, bfr, acc[0][f]);
      acc[1][f] = MFMA(a1, bfr, acc[1][f]);
    }
  }

  float w2v[NFRAG], bv[NFRAG];
#pragma unroll
  for (int f = 0; f < NFRAG; ++f) {
    w2v[f] = W2[f * 16 + l15];
    bv[f]  = bias_eff[f * 16 + l15];
  }
  const float bias2 = b2[0];

  float part[2][4];
#pragma unroll
  for (int m = 0; m < 2; ++m)
#pragma unroll
    for (int r = 0; r < 4; ++r) {
      float s = 0.f;
#pragma unroll
      for (int f = 0; f < NFRAG; ++f) {
        float h = acc[m][f][r] + bv[f];
        h = fmaxf(h, 0.f);
        s = fmaf(h, w2v[f], s);
      }
      part[m][r] = s;
    }

#pragma unroll
  for (int mask = 1; mask < 16; mask <<= 1)
#pragma unroll
    for (int m = 0; m < 2; ++m)
#pragma unroll
      for (int r = 0; r < 4; ++r)
        part[m][r] += __shfl_xor(part[m][r], mask, 64);

  if (l15 == 0) {
#pragma unroll
    for (int m = 0; m < 2; ++m)
#pragma unroll
      for (int r = 0; r < 4; ++r) {
        float x = part[m][r] + bias2;
        out[ebase + m * 16 + kg * 4 + r] = 1.f / (1.f + __expf(-x));
      }
  }
}

extern "C" void kernel_launch(void* const* d_in, const int* in_sizes, int n_in,
                              void* d_out, int out_size, void* d_ws, size_t ws_size,
                              hipStream_t stream) {
  const float* nodef  = (const float*)d_in[0];
  const float* eattr  = (const float*)d_in[1];
  const float* W_edge = (const float*)d_in[2];
  const float* b_edge = (const float*)d_in[3];
  const float* W1     = (const float*)d_in[4];
  const float* b1     = (const float*)d_in[5];
  const float* W2     = (const float*)d_in[6];
  const float* b2     = (const float*)d_in[7];
  const void*  eidx   = d_in[8];

  unsigned short* Bpack    = (unsigned short*)d_ws;
  float*          bias_eff = (float*)((char*)d_ws + BIAS_OFF_BYTES);
  int*            flag64   = (int*)((char*)d_ws + FLAG_OFF_BYTES);
  unsigned short* nbf      = (unsigned short*)((char*)d_ws + NODE_OFF_BYTES);
  int*            idx32    = (int*)((char*)d_ws + IDX_OFF_BYTES);

  setup_kernel<<<dim3(37), dim3(128), 0, stream>>>(W_edge, b_edge, W1, b1, eidx,
                                                   Bpack, bias_eff, flag64);

  if (ws_size >= (size_t)WS_NEEDED) {
    cvt_idx_kernel<<<dim3((2 * NEDGE + 255) / 256), dim3(256), 0, stream>>>(eidx, flag64, idx32);
    cvt_nodes_kernel<<<dim3((NNODE * HIDDEN / 8 + 255) / 256), dim3(256), 0, stream>>>(nodef, nbf);
    edge_attn_kernel<<<dim3(GRID_MAIN), dim3(256), 0, stream>>>(
        nbf, eattr, idx32, Bpack, bias_eff, W2, b2, (float*)d_out);
  } else {
    edge_attn_kernel_fp32<<<dim3(NEDGE / 128), dim3(256), 0, stream>>>(
        nodef, eattr, eidx, Bpack, bias_eff, W2, b2, flag64, (float*)d_out);
  }
}

// Round 6
// 342.811 us; speedup vs baseline: 1.0299x; 1.0299x over previous
//
#include <hip/hip_runtime.h>
#include <hip/hip_bf16.h>

#define HIDDEN   128
#define EDGE_DIM 32
#define NNODE    50000
#define NEDGE    800000
#define KSTEPS   9          // K = 288 = 9*32  (128 src + 128 dst + 32 edge_attr)
#define NFRAG    8          // 128 output cols / 16
#define LDS_KS   8          // K-steps staged in LDS (8*8KB = 65536 B, static max)
#define NGROUP   (NEDGE / 128)   // 6250 groups of 128 edges
#define GRID_MAIN 512            // 2 resident blocks per CU

typedef __attribute__((ext_vector_type(4))) float        f32x4;
typedef __attribute__((ext_vector_type(8))) short        bf16x8;
typedef __attribute__((ext_vector_type(4))) unsigned int u32x4;

#define BPACK_USHORTS  (KSTEPS * NFRAG * 64 * 8)   // 36864 bf16 = 73728 B
#define BIAS_OFF_BYTES (BPACK_USHORTS * 2)         // 73728
#define FLAG_OFF_BYTES (BIAS_OFF_BYTES + 128 * 4)  // 74240
#define NODE_OFF_BYTES 74752                       // 16B-aligned; bf16 nodes, 12.8 MB
#define IDX_OFF_BYTES  (NODE_OFF_BYTES + NNODE * HIDDEN * 2)   // 12874752
#define WS_NEEDED      (IDX_OFF_BYTES + 2 * NEDGE * 4)         // + 6.4 MB idx32

__device__ __forceinline__ unsigned short f2bf(float f) {
  unsigned u = __builtin_bit_cast(unsigned, f);
  u += 0x7FFFu + ((u >> 16) & 1u);   // RNE
  return (unsigned short)(u >> 16);
}

__device__ __forceinline__ unsigned cvt_pk_bf16(float a, float b) {
  union { __hip_bfloat162 h; unsigned u; } cv;
  cv.h = __float22bfloat162_rn(make_float2(a, b));   // v_cvt_pk_bf16_f32
  return cv.u;
}

__device__ __forceinline__ bf16x8 pack8(f32x4 lo, f32x4 hi) {
  u32x4 u;
  u[0] = cvt_pk_bf16(lo[0], lo[1]);
  u[1] = cvt_pk_bf16(lo[2], lo[3]);
  u[2] = cvt_pk_bf16(hi[0], hi[1]);
  u[3] = cvt_pk_bf16(hi[2], hi[3]);
  return __builtin_bit_cast(bf16x8, u);
}

// async global->LDS, 16B per lane, LDS dest = wave-uniform base + lane*16
__device__ __forceinline__ void gload_lds16(const void* g, void* l) {
  __builtin_amdgcn_global_load_lds(
      (const __attribute__((address_space(1))) unsigned int*)g,
      (__attribute__((address_space(3))) unsigned int*)l, 16, 0, 0);
}

#define MFMA(a, b, c) __builtin_amdgcn_mfma_f32_16x16x32_bf16((a), (b), (c), 0, 0, 0)

// ---- setup 1: folded, fragment-packed B (bf16) + effective bias + idx dtype flag
__global__ void setup_kernel(const float* __restrict__ W_edge,
                             const float* __restrict__ b_edge,
                             const float* __restrict__ W1,
                             const float* __restrict__ b1,
                             const void*  __restrict__ eidx,
                             unsigned short* __restrict__ Bpack,
                             float* __restrict__ bias_eff,
                             int*   __restrict__ flag64) {
  const int bid = blockIdx.x, tid = threadIdx.x;
  if (bid < 36) {
    const int pair  = bid * 2 + (tid >> 6);   // 0..71 = kstep*8 + nfrag
    const int lane  = tid & 63;
    const int kstep = pair >> 3;
    const int f     = pair & 7;
    const int col   = f * 16 + (lane & 15);
    const int kbase = kstep * 32 + (lane >> 4) * 8;
    float vals[8];
#pragma unroll
    for (int j = 0; j < 8; ++j) {
      const int k = kbase + j;
      float val;
      if (k < 128) {
        val = W1[k * 128 + col];
      } else if (k < 256) {
        val = W1[(k + 128) * 128 + col];
      } else {
        const int kk = k - 256;
        float s = 0.f;
        for (int t = 0; t < 128; ++t)
          s = fmaf(W_edge[kk * 128 + t], W1[(128 + t) * 128 + col], s);
        val = s;
      }
      vals[j] = val;
    }
    u32x4 sv;
#pragma unroll
    for (int j = 0; j < 4; ++j)
      sv[j] = (unsigned)f2bf(vals[2 * j]) | ((unsigned)f2bf(vals[2 * j + 1]) << 16);
    *(u32x4*)(Bpack + ((kstep * NFRAG + f) * 64 + lane) * 8) = sv;
  } else {
    if (tid < 128) {
      float s = b1[tid];
      for (int t = 0; t < 128; ++t)
        s = fmaf(b_edge[t], W1[(128 + t) * 128 + tid], s);
      bias_eff[tid] = s;
    }
    if (tid == 0) {
      const unsigned* w = (const unsigned*)eidx;
      int all0 = 1;
      for (int i = 0; i < 64; ++i) all0 &= (w[2 * i + 1] == 0u) ? 1 : 0;
      *flag64 = all0;
    }
  }
}

// ---- setup 2: node_features fp32 -> bf16 (row-major, same layout)
__global__ __launch_bounds__(256) void cvt_nodes_kernel(const float* __restrict__ nodef,
                                                        unsigned short* __restrict__ nbf) {
  const int i = blockIdx.x * 256 + threadIdx.x;   // one 8-elem chunk per thread
  if (i >= NNODE * HIDDEN / 8) return;
  f32x4 lo = *(const f32x4*)(nodef + i * 8);
  f32x4 hi = *(const f32x4*)(nodef + i * 8 + 4);
  *(bf16x8*)(nbf + i * 8) = pack8(lo, hi);
}

// ---- setup 3: edge_index (int64 or int32) -> int32 in ws
__global__ __launch_bounds__(256) void cvt_idx_kernel(const void* __restrict__ eidx,
                                                      const int* __restrict__ flag64,
                                                      int* __restrict__ idx32) {
  const int i = blockIdx.x * 256 + threadIdx.x;
  if (i >= 2 * NEDGE) return;
  if (*flag64) idx32[i] = (int)((const long long*)eidx)[i];
  else         idx32[i] = ((const int*)eidx)[i];
}

// ---- main: persistent blocks, B staged once, barrier-free group loop.
// NO cross-iteration register prefetch (round-5 spill lesson); only a 1-deep
// scalar idx prefetch. Peak liveness ~210 regs < 256 budget at (256,2).
__global__ __launch_bounds__(256, 2) void edge_attn_kernel(
    const unsigned short* __restrict__ nbf,
    const float* __restrict__ eattr,
    const int*   __restrict__ idx32,
    const unsigned short* __restrict__ Bpack,
    const float* __restrict__ bias_eff,
    const float* __restrict__ W2,
    const float* __restrict__ b2,
    float* __restrict__ out) {
  __shared__ unsigned short lds_b[LDS_KS * NFRAG * 64 * 8];   // 65536 B

  const int tid  = threadIdx.x;
  const int lane = tid & 63;
  const int wid  = tid >> 6;                 // 0..3
  const int l15  = lane & 15;
  const int kg   = lane >> 4;                // 0..3
  const int lofs = wid * 32 + l15;

  // stage B ks0..7 into LDS once (async, drained by the single barrier)
#pragma unroll
  for (int i = 0; i < 16; ++i) {
    const char* g = (const char*)Bpack + (size_t)(i * 256 + tid) * 16;
    char*       l = (char*)lds_b + (size_t)(i * 256 + wid * 64) * 16;
    gload_lds16(g, l);
  }

  // persistent registers: ks8 B-frags, W2, bias
  bf16x8 bfr8[NFRAG];
#pragma unroll
  for (int f = 0; f < NFRAG; ++f)
    bfr8[f] = *(const bf16x8*)(Bpack + ((8 * NFRAG + f) * 64 + lane) * 8);
  float w2v[NFRAG], bv[NFRAG];
#pragma unroll
  for (int f = 0; f < NFRAG; ++f) {
    w2v[f] = W2[f * 16 + l15];
    bv[f]  = bias_eff[f * 16 + l15];
  }
  const float bias2 = b2[0];

  __syncthreads();   // the only barrier

  // prologue: idx for first group
  int g = blockIdx.x;
  int rA0 = idx32[g * 128 + lofs];
  int rA1 = idx32[g * 128 + lofs + 16];
  int cA0 = idx32[NEDGE + g * 128 + lofs];
  int cA1 = idx32[NEDGE + g * 128 + lofs + 16];

#pragma unroll 1
  for (; g < NGROUP; g += GRID_MAIN) {
    // ---- issue all loads for this group: src, dst, eattr ----
    bf16x8 as0[4], as1[4], ad0[4], ad1[4];
#pragma unroll
    for (int ks = 0; ks < 4; ++ks) {
      as0[ks] = *(const bf16x8*)(nbf + (size_t)rA0 * HIDDEN + kg * 8 + ks * 32);
      as1[ks] = *(const bf16x8*)(nbf + (size_t)rA1 * HIDDEN + kg * 8 + ks * 32);
    }
#pragma unroll
    for (int ks = 0; ks < 4; ++ks) {
      ad0[ks] = *(const bf16x8*)(nbf + (size_t)cA0 * HIDDEN + kg * 8 + ks * 32);
      ad1[ks] = *(const bf16x8*)(nbf + (size_t)cA1 * HIDDEN + kg * 8 + ks * 32);
    }
    const float* pe0 = eattr + (size_t)(g * 128 + lofs) * EDGE_DIM + kg * 8;
    const float* pe1 = pe0 + 16 * EDGE_DIM;
    f32x4 ea0lo = *(const f32x4*)(pe0);
    f32x4 ea0hi = *(const f32x4*)(pe0 + 4);
    f32x4 ea1lo = *(const f32x4*)(pe1);
    f32x4 ea1hi = *(const f32x4*)(pe1 + 4);

    // idx prefetch for next iteration (scalar ints only)
    int gN = g + GRID_MAIN; if (gN >= NGROUP) gN = g;
    const int rN0 = idx32[gN * 128 + lofs];
    const int rN1 = idx32[gN * 128 + lofs + 16];
    const int cN0 = idx32[NEDGE + gN * 128 + lofs];
    const int cN1 = idx32[NEDGE + gN * 128 + lofs + 16];

    // acc init with folded bias
    f32x4 acc[2][NFRAG];
#pragma unroll
    for (int m = 0; m < 2; ++m)
#pragma unroll
      for (int f = 0; f < NFRAG; ++f)
        acc[m][f] = (f32x4){bv[f], bv[f], bv[f], bv[f]};

    // phase 1: src rows, ks 0..3 (B from LDS)
#pragma unroll
    for (int ks = 0; ks < 4; ++ks)
#pragma unroll
      for (int f = 0; f < NFRAG; ++f) {
        bf16x8 bfr = *(const bf16x8*)(lds_b + ((ks * NFRAG + f) * 64 + lane) * 8);
        acc[0][f] = MFMA(as0[ks], bfr, acc[0][f]);
        acc[1][f] = MFMA(as1[ks], bfr, acc[1][f]);
      }

    // phase 2: dst rows, ks 4..7 (B from LDS)
#pragma unroll
    for (int ks = 0; ks < 4; ++ks)
#pragma unroll
      for (int f = 0; f < NFRAG; ++f) {
        bf16x8 bfr = *(const bf16x8*)(lds_b + (((ks + 4) * NFRAG + f) * 64 + lane) * 8);
        acc[0][f] = MFMA(ad0[ks], bfr, acc[0][f]);
        acc[1][f] = MFMA(ad1[ks], bfr, acc[1][f]);
      }

    // phase 3: edge_attr, ks 8 (B from persistent regs)
    {
      bf16x8 ae0 = pack8(ea0lo, ea0hi);
      bf16x8 ae1 = pack8(ea1lo, ea1hi);
#pragma unroll
      for (int f = 0; f < NFRAG; ++f) {
        acc[0][f] = MFMA(ae0, bfr8[f], acc[0][f]);
        acc[1][f] = MFMA(ae1, bfr8[f], acc[1][f]);
      }
    }

    // epilogue: ReLU + dot(W2), 16-lane xor-reduce, sigmoid, store
    float part[2][4];
#pragma unroll
    for (int m = 0; m < 2; ++m)
#pragma unroll
      for (int r = 0; r < 4; ++r) {
        float s = 0.f;
#pragma unroll
        for (int f = 0; f < NFRAG; ++f) {
          float h = fmaxf(acc[m][f][r], 0.f);
          s = fmaf(h, w2v[f], s);
        }
        part[m][r] = s;
      }
#pragma unroll
    for (int mask = 1; mask < 16; mask <<= 1)
#pragma unroll
      for (int m = 0; m < 2; ++m)
#pragma unroll
        for (int r = 0; r < 4; ++r)
          part[m][r] += __shfl_xor(part[m][r], mask, 64);

    if (l15 == 0) {
      const int obase = g * 128 + wid * 32;
#pragma unroll
      for (int m = 0; m < 2; ++m)
#pragma unroll
        for (int r = 0; r < 4; ++r) {
          float x = part[m][r] + bias2;
          out[obase + m * 16 + kg * 4 + r] = 1.f / (1.f + __expf(-x));
        }
    }

    // rotate idx pipeline (1-deep)
    rA0 = rN0; rA1 = rN1; cA0 = cN0; cA1 = cN1;
  }
}

// ---- fallback main (round-1 style, fp32 gathers) in case ws is too small
__global__ __launch_bounds__(256) void edge_attn_kernel_fp32(
    const float* __restrict__ nodef,
    const float* __restrict__ eattr,
    const void*  __restrict__ eidx,
    const unsigned short* __restrict__ Bpack,
    const float* __restrict__ bias_eff,
    const float* __restrict__ W2,
    const float* __restrict__ b2,
    const int*   __restrict__ flag64,
    float* __restrict__ out) {
  const int lane  = threadIdx.x & 63;
  const int wid   = threadIdx.x >> 6;
  const int ebase = blockIdx.x * 128 + wid * 32;
  const int l15   = lane & 15;
  const int kg    = lane >> 4;
  const int koff  = kg * 8;
  const int e0 = ebase + l15;
  const int e1 = e0 + 16;

  long r0, c0, r1, c1;
  if (*flag64) {
    const long long* p = (const long long*)eidx;
    r0 = (long)p[e0];          r1 = (long)p[e1];
    c0 = (long)p[NEDGE + e0];  c1 = (long)p[NEDGE + e1];
  } else {
    const int* p = (const int*)eidx;
    r0 = p[e0];          r1 = p[e1];
    c0 = p[NEDGE + e0];  c1 = p[NEDGE + e1];
  }

  f32x4 acc[2][NFRAG];
#pragma unroll
  for (int m = 0; m < 2; ++m)
#pragma unroll
    for (int f = 0; f < NFRAG; ++f)
      acc[m][f] = (f32x4){0.f, 0.f, 0.f, 0.f};

#pragma unroll 1
  for (int ks = 0; ks < KSTEPS; ++ks) {
    const float *p0, *p1;
    if (ks < 4)      { p0 = nodef + r0 * HIDDEN + ks * 32;       p1 = nodef + r1 * HIDDEN + ks * 32; }
    else if (ks < 8) { p0 = nodef + c0 * HIDDEN + (ks - 4) * 32; p1 = nodef + c1 * HIDDEN + (ks - 4) * 32; }
    else             { p0 = eattr + (long)e0 * EDGE_DIM;         p1 = eattr + (long)e1 * EDGE_DIM; }

    f32x4 lo0 = *(const f32x4*)(p0 + koff);
    f32x4 hi0 = *(const f32x4*)(p0 + koff + 4);
    f32x4 lo1 = *(const f32x4*)(p1 + koff);
    f32x4 hi1 = *(const f32x4*)(p1 + koff + 4);
    bf16x8 a0 = pack8(lo0, hi0);
    bf16x8 a1 = pack8(lo1, hi1);

#pragma unroll
    for (int f = 0; f < NFRAG; ++f) {
      bf16x8 bfr = *(const bf16x8*)(Bpack + ((ks * NFRAG + f) * 64 + lane) * 8);
      acc[0][f] = MFMA(a0, bfr, acc[0][f]);
      acc[1][f] = MFMA(a1, bfr, acc[1][f]);
    }
  }

  float w2v[NFRAG], bv[NFRAG];
#pragma unroll
  for (int f = 0; f < NFRAG; ++f) {
    w2v[f] = W2[f * 16 + l15];
    bv[f]  = bias_eff[f * 16 + l15];
  }
  const float bias2 = b2[0];

  float part[2][4];
#pragma unroll
  for (int m = 0; m < 2; ++m)
#pragma unroll
    for (int r = 0; r < 4; ++r) {
      float s = 0.f;
#pragma unroll
      for (int f = 0; f < NFRAG; ++f) {
        float h = acc[m][f][r] + bv[f];
        h = fmaxf(h, 0.f);
        s = fmaf(h, w2v[f], s);
      }
      part[m][r] = s;
    }

#pragma unroll
  for (int mask = 1; mask < 16; mask <<= 1)
#pragma unroll
    for (int m = 0; m < 2; ++m)
#pragma unroll
      for (int r = 0; r < 4; ++r)
        part[m][r] += __shfl_xor(part[m][r], mask, 64);

  if (l15 == 0) {
#pragma unroll
    for (int m = 0; m < 2; ++m)
#pragma unroll
      for (int r = 0; r < 4; ++r) {
        float x = part[m][r] + bias2;
        out[ebase + m * 16 + kg * 4 + r] = 1.f / (1.f + __expf(-x));
      }
  }
}

extern "C" void kernel_launch(void* const* d_in, const int* in_sizes, int n_in,
                              void* d_out, int out_size, void* d_ws, size_t ws_size,
                              hipStream_t stream) {
  const float* nodef  = (const float*)d_in[0];
  const float* eattr  = (const float*)d_in[1];
  const float* W_edge = (const float*)d_in[2];
  const float* b_edge = (const float*)d_in[3];
  const float* W1     = (const float*)d_in[4];
  const float* b1     = (const float*)d_in[5];
  const float* W2     = (const float*)d_in[6];
  const float* b2     = (const float*)d_in[7];
  const void*  eidx   = d_in[8];

  unsigned short* Bpack    = (unsigned short*)d_ws;
  float*          bias_eff = (float*)((char*)d_ws + BIAS_OFF_BYTES);
  int*            flag64   = (int*)((char*)d_ws + FLAG_OFF_BYTES);
  unsigned short* nbf      = (unsigned short*)((char*)d_ws + NODE_OFF_BYTES);
  int*            idx32    = (int*)((char*)d_ws + IDX_OFF_BYTES);

  setup_kernel<<<dim3(37), dim3(128), 0, stream>>>(W_edge, b_edge, W1, b1, eidx,
                                                   Bpack, bias_eff, flag64);

  if (ws_size >= (size_t)WS_NEEDED) {
    cvt_idx_kernel<<<dim3((2 * NEDGE + 255) / 256), dim3(256), 0, stream>>>(eidx, flag64, idx32);
    cvt_nodes_kernel<<<dim3((NNODE * HIDDEN / 8 + 255) / 256), dim3(256), 0, stream>>>(nodef, nbf);
    edge_attn_kernel<<<dim3(GRID_MAIN), dim3(256), 0, stream>>>(
        nbf, eattr, idx32, Bpack, bias_eff, W2, b2, (float*)d_out);
  } else {
    edge_attn_kernel_fp32<<<dim3(NEDGE / 128), dim3(256), 0, stream>>>(
        nodef, eattr, eidx, Bpack, bias_eff, W2, b2, flag64, (float*)d_out);
  }
}

// Round 7
// 132.411 us; speedup vs baseline: 2.6663x; 2.5890x over previous
//
#include <hip/hip_runtime.h>
#include <hip/hip_bf16.h>

#define HIDDEN   128
#define EDGE_DIM 32
#define NNODE    50000
#define NEDGE    800000
#define KSTEPS   9          // K = 288 = 9*32  (128 src + 128 dst + 32 edge_attr)
#define NFRAG    8          // 128 output cols / 16
#define LDS_KS   8          // K-steps staged in LDS (8*8KB = 65536 B, static max)

typedef __attribute__((ext_vector_type(4))) float        f32x4;
typedef __attribute__((ext_vector_type(8))) short        bf16x8;
typedef __attribute__((ext_vector_type(4))) unsigned int u32x4;

#define BPACK_USHORTS  (KSTEPS * NFRAG * 64 * 8)   // 36864 bf16 = 73728 B
#define BIAS_OFF_BYTES (BPACK_USHORTS * 2)         // 73728
#define FLAG_OFF_BYTES (BIAS_OFF_BYTES + 128 * 4)  // 74240
#define NODE_OFF_BYTES 74752                       // 16B-aligned; bf16 nodes, 12.8 MB
#define IDX_OFF_BYTES  (NODE_OFF_BYTES + NNODE * HIDDEN * 2)   // 12874752
#define WS_NEEDED      (IDX_OFF_BYTES + 2 * NEDGE * 4)         // + 6.4 MB idx32

__device__ __forceinline__ unsigned short f2bf(float f) {
  unsigned u = __builtin_bit_cast(unsigned, f);
  u += 0x7FFFu + ((u >> 16) & 1u);   // RNE
  return (unsigned short)(u >> 16);
}

__device__ __forceinline__ unsigned cvt_pk_bf16(float a, float b) {
  union { __hip_bfloat162 h; unsigned u; } cv;
  cv.h = __float22bfloat162_rn(make_float2(a, b));   // v_cvt_pk_bf16_f32
  return cv.u;
}

__device__ __forceinline__ bf16x8 pack8(f32x4 lo, f32x4 hi) {
  u32x4 u;
  u[0] = cvt_pk_bf16(lo[0], lo[1]);
  u[1] = cvt_pk_bf16(lo[2], lo[3]);
  u[2] = cvt_pk_bf16(hi[0], hi[1]);
  u[3] = cvt_pk_bf16(hi[2], hi[3]);
  return __builtin_bit_cast(bf16x8, u);
}

// async global->LDS, 16B per lane, LDS dest = wave-uniform base + lane*16
__device__ __forceinline__ void gload_lds16(const void* g, void* l) {
  __builtin_amdgcn_global_load_lds(
      (const __attribute__((address_space(1))) unsigned int*)g,
      (__attribute__((address_space(3))) unsigned int*)l, 16, 0, 0);
}

#define MFMA(a, b, c) __builtin_amdgcn_mfma_f32_16x16x32_bf16((a), (b), (c), 0, 0, 0)

// ---- setup 1: folded, fragment-packed B (bf16) + effective bias + idx dtype flag
__global__ void setup_kernel(const float* __restrict__ W_edge,
                             const float* __restrict__ b_edge,
                             const float* __restrict__ W1,
                             const float* __restrict__ b1,
                             const void*  __restrict__ eidx,
                             unsigned short* __restrict__ Bpack,
                             float* __restrict__ bias_eff,
                             int*   __restrict__ flag64) {
  const int bid = blockIdx.x, tid = threadIdx.x;
  if (bid < 36) {
    const int pair  = bid * 2 + (tid >> 6);   // 0..71 = kstep*8 + nfrag
    const int lane  = tid & 63;
    const int kstep = pair >> 3;
    const int f     = pair & 7;
    const int col   = f * 16 + (lane & 15);
    const int kbase = kstep * 32 + (lane >> 4) * 8;
    float vals[8];
#pragma unroll
    for (int j = 0; j < 8; ++j) {
      const int k = kbase + j;
      float val;
      if (k < 128) {
        val = W1[k * 128 + col];
      } else if (k < 256) {
        val = W1[(k + 128) * 128 + col];
      } else {
        const int kk = k - 256;
        float s = 0.f;
        for (int t = 0; t < 128; ++t)
          s = fmaf(W_edge[kk * 128 + t], W1[(128 + t) * 128 + col], s);
        val = s;
      }
      vals[j] = val;
    }
    u32x4 sv;
#pragma unroll
    for (int j = 0; j < 4; ++j)
      sv[j] = (unsigned)f2bf(vals[2 * j]) | ((unsigned)f2bf(vals[2 * j + 1]) << 16);
    *(u32x4*)(Bpack + ((kstep * NFRAG + f) * 64 + lane) * 8) = sv;
  } else {
    if (tid < 128) {
      float s = b1[tid];
      for (int t = 0; t < 128; ++t)
        s = fmaf(b_edge[t], W1[(128 + t) * 128 + tid], s);
      bias_eff[tid] = s;
    }
    if (tid == 0) {
      const unsigned* w = (const unsigned*)eidx;
      int all0 = 1;
      for (int i = 0; i < 64; ++i) all0 &= (w[2 * i + 1] == 0u) ? 1 : 0;
      *flag64 = all0;
    }
  }
}

// ---- setup 2: node_features fp32 -> bf16 (row-major, same layout)
__global__ __launch_bounds__(256) void cvt_nodes_kernel(const float* __restrict__ nodef,
                                                        unsigned short* __restrict__ nbf) {
  const int i = blockIdx.x * 256 + threadIdx.x;   // one 8-elem chunk per thread
  if (i >= NNODE * HIDDEN / 8) return;
  f32x4 lo = *(const f32x4*)(nodef + i * 8);
  f32x4 hi = *(const f32x4*)(nodef + i * 8 + 4);
  *(bf16x8*)(nbf + i * 8) = pack8(lo, hi);
}

// ---- setup 3: edge_index (int64 or int32) -> int32 in ws
__global__ __launch_bounds__(256) void cvt_idx_kernel(const void* __restrict__ eidx,
                                                      const int* __restrict__ flag64,
                                                      int* __restrict__ idx32) {
  const int i = blockIdx.x * 256 + threadIdx.x;
  if (i >= 2 * NEDGE) return;
  if (*flag64) idx32[i] = (int)((const long long*)eidx)[i];
  else         idx32[i] = ((const int*)eidx)[i];
}

// ---- main: FLAT grid (3125 blocks), 4 waves x 64 edges = 256 edges/block.
// One staging+barrier per 256 edges. Phases strictly serialized (sched_barrier)
// so src A-regs are dead before dst gathers issue: peak liveness ~210 < 256.
__global__ __launch_bounds__(256, 2) void edge_attn_kernel(
    const unsigned short* __restrict__ nbf,
    const float* __restrict__ eattr,
    const int*   __restrict__ idx32,
    const unsigned short* __restrict__ Bpack,
    const float* __restrict__ bias_eff,
    const float* __restrict__ W2,
    const float* __restrict__ b2,
    float* __restrict__ out) {
  __shared__ unsigned short lds_b[LDS_KS * NFRAG * 64 * 8];   // 65536 B

  const int tid   = threadIdx.x;
  const int lane  = tid & 63;
  const int wid   = tid >> 6;                 // 0..3
  const int l15   = lane & 15;
  const int kg    = lane >> 4;                // 0..3
  const int ebase = blockIdx.x * 256 + wid * 64;   // 64 edges per wave

  // stage B ks0..7 into LDS (async; drained by the single barrier)
#pragma unroll
  for (int i = 0; i < 16; ++i) {
    const char* g = (const char*)Bpack + (size_t)(i * 256 + tid) * 16;
    char*       l = (char*)lds_b + (size_t)(i * 256 + wid * 64) * 16;
    gload_lds16(g, l);
  }

  // indices for this wave's 64 edges (4 M-frags of 16)
  int r[4], c[4];
#pragma unroll
  for (int mf = 0; mf < 4; ++mf) {
    r[mf] = idx32[ebase + mf * 16 + l15];
    c[mf] = idx32[NEDGE + ebase + mf * 16 + l15];
  }

  // src gathers (issued pre-barrier; latency hides under staging drain)
  bf16x8 a[4][4];   // [mf][ks]
#pragma unroll
  for (int mf = 0; mf < 4; ++mf)
#pragma unroll
    for (int ks = 0; ks < 4; ++ks)
      a[mf][ks] = *(const bf16x8*)(nbf + (size_t)r[mf] * HIDDEN + kg * 8 + ks * 32);

  __syncthreads();   // drains vmcnt (staging + gathers) + lgkmcnt

  f32x4 acc[4][NFRAG];
#pragma unroll
  for (int mf = 0; mf < 4; ++mf)
#pragma unroll
    for (int f = 0; f < NFRAG; ++f)
      acc[mf][f] = (f32x4){0.f, 0.f, 0.f, 0.f};

  // phase 1: src rows, ks 0..3 (B from LDS)
#pragma unroll
  for (int ks = 0; ks < 4; ++ks)
#pragma unroll
    for (int f = 0; f < NFRAG; ++f) {
      bf16x8 bfr = *(const bf16x8*)(lds_b + ((ks * NFRAG + f) * 64 + lane) * 8);
#pragma unroll
      for (int mf = 0; mf < 4; ++mf)
        acc[mf][f] = MFMA(a[mf][ks], bfr, acc[mf][f]);
    }

  // fence: keep dst gathers below phase-1 MFMAs (a[][] must be dead first)
  __builtin_amdgcn_sched_barrier(0);

  // dst gathers into the SAME registers (src set is dead)
#pragma unroll
  for (int mf = 0; mf < 4; ++mf)
#pragma unroll
    for (int ks = 0; ks < 4; ++ks)
      a[mf][ks] = *(const bf16x8*)(nbf + (size_t)c[mf] * HIDDEN + kg * 8 + ks * 32);

  // phase 2: dst rows, ks 4..7 (B from LDS)
#pragma unroll
  for (int ks = 0; ks < 4; ++ks)
#pragma unroll
    for (int f = 0; f < NFRAG; ++f) {
      bf16x8 bfr = *(const bf16x8*)(lds_b + (((ks + 4) * NFRAG + f) * 64 + lane) * 8);
#pragma unroll
      for (int mf = 0; mf < 4; ++mf)
        acc[mf][f] = MFMA(a[mf][ks], bfr, acc[mf][f]);
    }

  __builtin_amdgcn_sched_barrier(0);

  // phase 3: edge_attr, ks 8 (eattr fp32 -> bf16; B-frags from L2-hot global)
  bf16x8 ae[4];
#pragma unroll
  for (int mf = 0; mf < 4; ++mf) {
    const float* pe = eattr + (size_t)(ebase + mf * 16 + l15) * EDGE_DIM + kg * 8;
    f32x4 lo = *(const f32x4*)(pe);
    f32x4 hi = *(const f32x4*)(pe + 4);
    ae[mf] = pack8(lo, hi);
  }
#pragma unroll
  for (int f = 0; f < NFRAG; ++f) {
    bf16x8 bfr = *(const bf16x8*)(Bpack + ((8 * NFRAG + f) * 64 + lane) * 8);
#pragma unroll
    for (int mf = 0; mf < 4; ++mf)
      acc[mf][f] = MFMA(ae[mf], bfr, acc[mf][f]);
  }

  // epilogue: bias + ReLU + dot(W2), 16-lane xor-reduce, sigmoid, store
  float w2v[NFRAG], bv[NFRAG];
#pragma unroll
  for (int f = 0; f < NFRAG; ++f) {
    w2v[f] = W2[f * 16 + l15];
    bv[f]  = bias_eff[f * 16 + l15];
  }
  const float bias2 = b2[0];

  float part[4][4];
#pragma unroll
  for (int mf = 0; mf < 4; ++mf)
#pragma unroll
    for (int rr = 0; rr < 4; ++rr) {
      float s = 0.f;
#pragma unroll
      for (int f = 0; f < NFRAG; ++f) {
        float h = fmaxf(acc[mf][f][rr] + bv[f], 0.f);
        s = fmaf(h, w2v[f], s);
      }
      part[mf][rr] = s;
    }

#pragma unroll
  for (int mask = 1; mask < 16; mask <<= 1)
#pragma unroll
    for (int mf = 0; mf < 4; ++mf)
#pragma unroll
      for (int rr = 0; rr < 4; ++rr)
        part[mf][rr] += __shfl_xor(part[mf][rr], mask, 64);

  if (l15 == 0) {
#pragma unroll
    for (int mf = 0; mf < 4; ++mf)
#pragma unroll
      for (int rr = 0; rr < 4; ++rr) {
        float x = part[mf][rr] + bias2;
        out[ebase + mf * 16 + kg * 4 + rr] = 1.f / (1.f + __expf(-x));
      }
  }
}

// ---- fallback main (round-1 style, fp32 gathers) in case ws is too small
__global__ __launch_bounds__(256) void edge_attn_kernel_fp32(
    const float* __restrict__ nodef,
    const float* __restrict__ eattr,
    const void*  __restrict__ eidx,
    const unsigned short* __restrict__ Bpack,
    const float* __restrict__ bias_eff,
    const float* __restrict__ W2,
    const float* __restrict__ b2,
    const int*   __restrict__ flag64,
    float* __restrict__ out) {
  const int lane  = threadIdx.x & 63;
  const int wid   = threadIdx.x >> 6;
  const int ebase = blockIdx.x * 128 + wid * 32;
  const int l15   = lane & 15;
  const int kg    = lane >> 4;
  const int koff  = kg * 8;
  const int e0 = ebase + l15;
  const int e1 = e0 + 16;

  long r0, c0, r1, c1;
  if (*flag64) {
    const long long* p = (const long long*)eidx;
    r0 = (long)p[e0];          r1 = (long)p[e1];
    c0 = (long)p[NEDGE + e0];  c1 = (long)p[NEDGE + e1];
  } else {
    const int* p = (const int*)eidx;
    r0 = p[e0];          r1 = p[e1];
    c0 = p[NEDGE + e0];  c1 = p[NEDGE + e1];
  }

  f32x4 acc[2][NFRAG];
#pragma unroll
  for (int m = 0; m < 2; ++m)
#pragma unroll
    for (int f = 0; f < NFRAG; ++f)
      acc[m][f] = (f32x4){0.f, 0.f, 0.f, 0.f};

#pragma unroll 1
  for (int ks = 0; ks < KSTEPS; ++ks) {
    const float *p0, *p1;
    if (ks < 4)      { p0 = nodef + r0 * HIDDEN + ks * 32;       p1 = nodef + r1 * HIDDEN + ks * 32; }
    else if (ks < 8) { p0 = nodef + c0 * HIDDEN + (ks - 4) * 32; p1 = nodef + c1 * HIDDEN + (ks - 4) * 32; }
    else             { p0 = eattr + (long)e0 * EDGE_DIM;         p1 = eattr + (long)e1 * EDGE_DIM; }

    f32x4 lo0 = *(const f32x4*)(p0 + koff);
    f32x4 hi0 = *(const f32x4*)(p0 + koff + 4);
    f32x4 lo1 = *(const f32x4*)(p1 + koff);
    f32x4 hi1 = *(const f32x4*)(p1 + koff + 4);
    bf16x8 a0 = pack8(lo0, hi0);
    bf16x8 a1 = pack8(lo1, hi1);

#pragma unroll
    for (int f = 0; f < NFRAG; ++f) {
      bf16x8 bfr = *(const bf16x8*)(Bpack + ((ks * NFRAG + f) * 64 + lane) * 8);
      acc[0][f] = MFMA(a0, bfr, acc[0][f]);
      acc[1][f] = MFMA(a1, bfr, acc[1][f]);
    }
  }

  float w2v[NFRAG], bv[NFRAG];
#pragma unroll
  for (int f = 0; f < NFRAG; ++f) {
    w2v[f] = W2[f * 16 + l15];
    bv[f]  = bias_eff[f * 16 + l15];
  }
  const float bias2 = b2[0];

  float part[2][4];
#pragma unroll
  for (int m = 0; m < 2; ++m)
#pragma unroll
    for (int r = 0; r < 4; ++r) {
      float s = 0.f;
#pragma unroll
      for (int f = 0; f < NFRAG; ++f) {
        float h = acc[m][f][r] + bv[f];
        h = fmaxf(h, 0.f);
        s = fmaf(h, w2v[f], s);
      }
      part[m][r] = s;
    }

#pragma unroll
  for (int mask = 1; mask < 16; mask <<= 1)
#pragma unroll
    for (int m = 0; m < 2; ++m)
#pragma unroll
      for (int r = 0; r < 4; ++r)
        part[m][r] += __shfl_xor(part[m][r], mask, 64);

  if (l15 == 0) {
#pragma unroll
    for (int m = 0; m < 2; ++m)
#pragma unroll
      for (int r = 0; r < 4; ++r) {
        float x = part[m][r] + bias2;
        out[ebase + m * 16 + kg * 4 + r] = 1.f / (1.f + __expf(-x));
      }
  }
}

extern "C" void kernel_launch(void* const* d_in, const int* in_sizes, int n_in,
                              void* d_out, int out_size, void* d_ws, size_t ws_size,
                              hipStream_t stream) {
  const float* nodef  = (const float*)d_in[0];
  const float* eattr  = (const float*)d_in[1];
  const float* W_edge = (const float*)d_in[2];
  const float* b_edge = (const float*)d_in[3];
  const float* W1     = (const float*)d_in[4];
  const float* b1     = (const float*)d_in[5];
  const float* W2     = (const float*)d_in[6];
  const float* b2     = (const float*)d_in[7];
  const void*  eidx   = d_in[8];

  unsigned short* Bpack    = (unsigned short*)d_ws;
  float*          bias_eff = (float*)((char*)d_ws + BIAS_OFF_BYTES);
  int*            flag64   = (int*)((char*)d_ws + FLAG_OFF_BYTES);
  unsigned short* nbf      = (unsigned short*)((char*)d_ws + NODE_OFF_BYTES);
  int*            idx32    = (int*)((char*)d_ws + IDX_OFF_BYTES);

  setup_kernel<<<dim3(37), dim3(128), 0, stream>>>(W_edge, b_edge, W1, b1, eidx,
                                                   Bpack, bias_eff, flag64);

  if (ws_size >= (size_t)WS_NEEDED) {
    cvt_idx_kernel<<<dim3((2 * NEDGE + 255) / 256), dim3(256), 0, stream>>>(eidx, flag64, idx32);
    cvt_nodes_kernel<<<dim3((NNODE * HIDDEN / 8 + 255) / 256), dim3(256), 0, stream>>>(nodef, nbf);
    edge_attn_kernel<<<dim3(NEDGE / 256), dim3(256), 0, stream>>>(
        nbf, eattr, idx32, Bpack, bias_eff, W2, b2, (float*)d_out);
  } else {
    edge_attn_kernel_fp32<<<dim3(NEDGE / 128), dim3(256), 0, stream>>>(
        nodef, eattr, eidx, Bpack, bias_eff, W2, b2, flag64, (float*)d_out);
  }
}

// Round 8
// 128.771 us; speedup vs baseline: 2.7417x; 1.0283x over previous
//
#include <hip/hip_runtime.h>
#include <hip/hip_bf16.h>

#define HIDDEN   128
#define EDGE_DIM 32
#define NNODE    50000
#define NEDGE    800000
#define KSTEPS   9          // K = 288 = 9*32  (128 src + 128 dst + 32 edge_attr)
#define NFRAG    8          // 128 output cols / 16
#define LDS_KS   8          // K-steps staged in LDS (8*8KB = 65536 B, static max)

typedef __attribute__((ext_vector_type(4))) float        f32x4;
typedef __attribute__((ext_vector_type(8))) short        bf16x8;
typedef __attribute__((ext_vector_type(4))) unsigned int u32x4;

#define BPACK_USHORTS  (KSTEPS * NFRAG * 64 * 8)   // 36864 bf16 = 73728 B
#define BIAS_OFF_BYTES (BPACK_USHORTS * 2)         // 73728
#define FLAG_OFF_BYTES (BIAS_OFF_BYTES + 128 * 4)  // 74240
#define NODE_OFF_BYTES 74752                       // 16B-aligned; bf16 nodes, 12.8 MB
#define IDX_OFF_BYTES  (NODE_OFF_BYTES + NNODE * HIDDEN * 2)   // 12874752
#define WS_NEEDED      (IDX_OFF_BYTES + 2 * NEDGE * 4)         // + 6.4 MB idx32

__device__ __forceinline__ unsigned short f2bf(float f) {
  unsigned u = __builtin_bit_cast(unsigned, f);
  u += 0x7FFFu + ((u >> 16) & 1u);   // RNE
  return (unsigned short)(u >> 16);
}

__device__ __forceinline__ unsigned cvt_pk_bf16(float a, float b) {
  union { __hip_bfloat162 h; unsigned u; } cv;
  cv.h = __float22bfloat162_rn(make_float2(a, b));   // v_cvt_pk_bf16_f32
  return cv.u;
}

__device__ __forceinline__ bf16x8 pack8(f32x4 lo, f32x4 hi) {
  u32x4 u;
  u[0] = cvt_pk_bf16(lo[0], lo[1]);
  u[1] = cvt_pk_bf16(lo[2], lo[3]);
  u[2] = cvt_pk_bf16(hi[0], hi[1]);
  u[3] = cvt_pk_bf16(hi[2], hi[3]);
  return __builtin_bit_cast(bf16x8, u);
}

// async global->LDS, 16B per lane, LDS dest = wave-uniform base + lane*16
__device__ __forceinline__ void gload_lds16(const void* g, void* l) {
  __builtin_amdgcn_global_load_lds(
      (const __attribute__((address_space(1))) unsigned int*)g,
      (__attribute__((address_space(3))) unsigned int*)l, 16, 0, 0);
}

#define MFMA(a, b, c) __builtin_amdgcn_mfma_f32_16x16x32_bf16((a), (b), (c), 0, 0, 0)

// ---- setup 1: folded, fragment-packed B (bf16) + effective bias + idx dtype flag
__global__ void setup_kernel(const float* __restrict__ W_edge,
                             const float* __restrict__ b_edge,
                             const float* __restrict__ W1,
                             const float* __restrict__ b1,
                             const void*  __restrict__ eidx,
                             unsigned short* __restrict__ Bpack,
                             float* __restrict__ bias_eff,
                             int*   __restrict__ flag64) {
  const int bid = blockIdx.x, tid = threadIdx.x;
  if (bid < 36) {
    const int pair  = bid * 2 + (tid >> 6);   // 0..71 = kstep*8 + nfrag
    const int lane  = tid & 63;
    const int kstep = pair >> 3;
    const int f     = pair & 7;
    const int col   = f * 16 + (lane & 15);
    const int kbase = kstep * 32 + (lane >> 4) * 8;
    float vals[8];
#pragma unroll
    for (int j = 0; j < 8; ++j) {
      const int k = kbase + j;
      float val;
      if (k < 128) {
        val = W1[k * 128 + col];
      } else if (k < 256) {
        val = W1[(k + 128) * 128 + col];
      } else {
        const int kk = k - 256;
        float s = 0.f;
        for (int t = 0; t < 128; ++t)
          s = fmaf(W_edge[kk * 128 + t], W1[(128 + t) * 128 + col], s);
        val = s;
      }
      vals[j] = val;
    }
    u32x4 sv;
#pragma unroll
    for (int j = 0; j < 4; ++j)
      sv[j] = (unsigned)f2bf(vals[2 * j]) | ((unsigned)f2bf(vals[2 * j + 1]) << 16);
    *(u32x4*)(Bpack + ((kstep * NFRAG + f) * 64 + lane) * 8) = sv;
  } else {
    if (tid < 128) {
      float s = b1[tid];
      for (int t = 0; t < 128; ++t)
        s = fmaf(b_edge[t], W1[(128 + t) * 128 + tid], s);
      bias_eff[tid] = s;
    }
    if (tid == 0) {
      const unsigned* w = (const unsigned*)eidx;
      int all0 = 1;
      for (int i = 0; i < 64; ++i) all0 &= (w[2 * i + 1] == 0u) ? 1 : 0;
      *flag64 = all0;
    }
  }
}

// ---- setup 2: node_features fp32 -> bf16 (row-major, same layout)
__global__ __launch_bounds__(256) void cvt_nodes_kernel(const float* __restrict__ nodef,
                                                        unsigned short* __restrict__ nbf) {
  const int i = blockIdx.x * 256 + threadIdx.x;   // one 8-elem chunk per thread
  if (i >= NNODE * HIDDEN / 8) return;
  f32x4 lo = *(const f32x4*)(nodef + i * 8);
  f32x4 hi = *(const f32x4*)(nodef + i * 8 + 4);
  *(bf16x8*)(nbf + i * 8) = pack8(lo, hi);
}

// ---- setup 3: edge_index (int64 or int32) -> int32 in ws
__global__ __launch_bounds__(256) void cvt_idx_kernel(const void* __restrict__ eidx,
                                                      const int* __restrict__ flag64,
                                                      int* __restrict__ idx32) {
  const int i = blockIdx.x * 256 + threadIdx.x;
  if (i >= 2 * NEDGE) return;
  if (*flag64) idx32[i] = (int)((const long long*)eidx)[i];
  else         idx32[i] = ((const int*)eidx)[i];
}

// ---- main: 512 threads = 8 waves x 32 edges = 256 edges/block, flat grid 3125.
// M=32/wave (acc 64 regs) + lean liveness (<=128 total) -> 4 waves/SIMD =
// 16 waves/CU (2 blocks x 64KB LDS). TLP hides gather/eattr latency.
__global__ __launch_bounds__(512, 4) void edge_attn_kernel(
    const unsigned short* __restrict__ nbf,
    const float* __restrict__ eattr,
    const int*   __restrict__ idx32,
    const unsigned short* __restrict__ Bpack,
    const float* __restrict__ bias_eff,
    const float* __restrict__ W2,
    const float* __restrict__ b2,
    float* __restrict__ out) {
  __shared__ unsigned short lds_b[LDS_KS * NFRAG * 64 * 8];   // 65536 B

  const int tid   = threadIdx.x;
  const int lane  = tid & 63;
  const int wid   = tid >> 6;                 // 0..7
  const int l15   = lane & 15;
  const int kg    = lane >> 4;                // 0..3
  const int ebase = blockIdx.x * 256 + wid * 32;   // 32 edges per wave

  // stage B ks0..7 into LDS (async; drained by the single barrier)
#pragma unroll
  for (int i = 0; i < 8; ++i) {
    const char* g = (const char*)Bpack + (size_t)(i * 512 + tid) * 16;
    char*       l = (char*)lds_b + (size_t)(i * 512 + wid * 64) * 16;
    gload_lds16(g, l);
  }

  // indices for this wave's 32 edges (2 M-frags of 16)
  const int r0 = idx32[ebase + l15];
  const int r1 = idx32[ebase + 16 + l15];
  const int c0 = idx32[NEDGE + ebase + l15];
  const int c1 = idx32[NEDGE + ebase + 16 + l15];

  // src gathers (pre-barrier; latency hides under staging drain)
  bf16x8 a0[4], a1[4];
#pragma unroll
  for (int ks = 0; ks < 4; ++ks) {
    a0[ks] = *(const bf16x8*)(nbf + (size_t)r0 * HIDDEN + kg * 8 + ks * 32);
    a1[ks] = *(const bf16x8*)(nbf + (size_t)r1 * HIDDEN + kg * 8 + ks * 32);
  }

  __syncthreads();   // drains vmcnt (staging + gathers) + lgkmcnt

  f32x4 acc[2][NFRAG];
#pragma unroll
  for (int m = 0; m < 2; ++m)
#pragma unroll
    for (int f = 0; f < NFRAG; ++f)
      acc[m][f] = (f32x4){0.f, 0.f, 0.f, 0.f};

  // phase 1: src rows, ks 0..3 (B from LDS)
#pragma unroll
  for (int ks = 0; ks < 4; ++ks)
#pragma unroll
    for (int f = 0; f < NFRAG; ++f) {
      bf16x8 bfr = *(const bf16x8*)(lds_b + ((ks * NFRAG + f) * 64 + lane) * 8);
      acc[0][f] = MFMA(a0[ks], bfr, acc[0][f]);
      acc[1][f] = MFMA(a1[ks], bfr, acc[1][f]);
    }

  // fence: keep dst gathers below phase-1 MFMAs (a regs must be dead first)
  __builtin_amdgcn_sched_barrier(0);

  // dst gathers into the SAME registers (src set is dead)
#pragma unroll
  for (int ks = 0; ks < 4; ++ks) {
    a0[ks] = *(const bf16x8*)(nbf + (size_t)c0 * HIDDEN + kg * 8 + ks * 32);
    a1[ks] = *(const bf16x8*)(nbf + (size_t)c1 * HIDDEN + kg * 8 + ks * 32);
  }

  // phase 2: dst rows, ks 4..7 (B from LDS)
#pragma unroll
  for (int ks = 0; ks < 4; ++ks)
#pragma unroll
    for (int f = 0; f < NFRAG; ++f) {
      bf16x8 bfr = *(const bf16x8*)(lds_b + (((ks + 4) * NFRAG + f) * 64 + lane) * 8);
      acc[0][f] = MFMA(a0[ks], bfr, acc[0][f]);
      acc[1][f] = MFMA(a1[ks], bfr, acc[1][f]);
    }

  __builtin_amdgcn_sched_barrier(0);

  // phase 3: edge_attr (loaded here; TLP covers the stall), ks8 B from
  // L1-hot global.
  bf16x8 ae0, ae1;
  {
    const float* pe = eattr + (size_t)(ebase + l15) * EDGE_DIM + kg * 8;
    f32x4 lo = *(const f32x4*)(pe);
    f32x4 hi = *(const f32x4*)(pe + 4);
    ae0 = pack8(lo, hi);
  }
  {
    const float* pe = eattr + (size_t)(ebase + 16 + l15) * EDGE_DIM + kg * 8;
    f32x4 lo = *(const f32x4*)(pe);
    f32x4 hi = *(const f32x4*)(pe + 4);
    ae1 = pack8(lo, hi);
  }
#pragma unroll
  for (int f = 0; f < NFRAG; ++f) {
    bf16x8 bfr = *(const bf16x8*)(Bpack + ((8 * NFRAG + f) * 64 + lane) * 8);
    acc[0][f] = MFMA(ae0, bfr, acc[0][f]);
    acc[1][f] = MFMA(ae1, bfr, acc[1][f]);
  }

  // epilogue: bias + ReLU + dot(W2), 16-lane xor-reduce, sigmoid, store
  float w2v[NFRAG], bv[NFRAG];
#pragma unroll
  for (int f = 0; f < NFRAG; ++f) {
    w2v[f] = W2[f * 16 + l15];
    bv[f]  = bias_eff[f * 16 + l15];
  }
  const float bias2 = b2[0];

  float part[2][4];
#pragma unroll
  for (int m = 0; m < 2; ++m)
#pragma unroll
    for (int rr = 0; rr < 4; ++rr) {
      float s = 0.f;
#pragma unroll
      for (int f = 0; f < NFRAG; ++f) {
        float h = fmaxf(acc[m][f][rr] + bv[f], 0.f);
        s = fmaf(h, w2v[f], s);
      }
      part[m][rr] = s;
    }

#pragma unroll
  for (int mask = 1; mask < 16; mask <<= 1)
#pragma unroll
    for (int m = 0; m < 2; ++m)
#pragma unroll
      for (int rr = 0; rr < 4; ++rr)
        part[m][rr] += __shfl_xor(part[m][rr], mask, 64);

  if (l15 == 0) {
#pragma unroll
    for (int m = 0; m < 2; ++m)
#pragma unroll
      for (int rr = 0; rr < 4; ++rr) {
        float x = part[m][rr] + bias2;
        out[ebase + m * 16 + kg * 4 + rr] = 1.f / (1.f + __expf(-x));
      }
  }
}

// ---- fallback main (round-1 style, fp32 gathers) in case ws is too small
__global__ __launch_bounds__(256) void edge_attn_kernel_fp32(
    const float* __restrict__ nodef,
    const float* __restrict__ eattr,
    const void*  __restrict__ eidx,
    const unsigned short* __restrict__ Bpack,
    const float* __restrict__ bias_eff,
    const float* __restrict__ W2,
    const float* __restrict__ b2,
    const int*   __restrict__ flag64,
    float* __restrict__ out) {
  const int lane  = threadIdx.x & 63;
  const int wid   = threadIdx.x >> 6;
  const int ebase = blockIdx.x * 128 + wid * 32;
  const int l15   = lane & 15;
  const int kg    = lane >> 4;
  const int koff  = kg * 8;
  const int e0 = ebase + l15;
  const int e1 = e0 + 16;

  long r0, c0, r1, c1;
  if (*flag64) {
    const long long* p = (const long long*)eidx;
    r0 = (long)p[e0];          r1 = (long)p[e1];
    c0 = (long)p[NEDGE + e0];  c1 = (long)p[NEDGE + e1];
  } else {
    const int* p = (const int*)eidx;
    r0 = p[e0];          r1 = p[e1];
    c0 = p[NEDGE + e0];  c1 = p[NEDGE + e1];
  }

  f32x4 acc[2][NFRAG];
#pragma unroll
  for (int m = 0; m < 2; ++m)
#pragma unroll
    for (int f = 0; f < NFRAG; ++f)
      acc[m][f] = (f32x4){0.f, 0.f, 0.f, 0.f};

#pragma unroll 1
  for (int ks = 0; ks < KSTEPS; ++ks) {
    const float *p0, *p1;
    if (ks < 4)      { p0 = nodef + r0 * HIDDEN + ks * 32;       p1 = nodef + r1 * HIDDEN + ks * 32; }
    else if (ks < 8) { p0 = nodef + c0 * HIDDEN + (ks - 4) * 32; p1 = nodef + c1 * HIDDEN + (ks - 4) * 32; }
    else             { p0 = eattr + (long)e0 * EDGE_DIM;         p1 = eattr + (long)e1 * EDGE_DIM; }

    f32x4 lo0 = *(const f32x4*)(p0 + koff);
    f32x4 hi0 = *(const f32x4*)(p0 + koff + 4);
    f32x4 lo1 = *(const f32x4*)(p1 + koff);
    f32x4 hi1 = *(const f32x4*)(p1 + koff + 4);
    bf16x8 a0 = pack8(lo0, hi0);
    bf16x8 a1 = pack8(lo1, hi1);

#pragma unroll
    for (int f = 0; f < NFRAG; ++f) {
      bf16x8 bfr = *(const bf16x8*)(Bpack + ((ks * NFRAG + f) * 64 + lane) * 8);
      acc[0][f] = MFMA(a0, bfr, acc[0][f]);
      acc[1][f] = MFMA(a1, bfr, acc[1][f]);
    }
  }

  float w2v[NFRAG], bv[NFRAG];
#pragma unroll
  for (int f = 0; f < NFRAG; ++f) {
    w2v[f] = W2[f * 16 + l15];
    bv[f]  = bias_eff[f * 16 + l15];
  }
  const float bias2 = b2[0];

  float part[2][4];
#pragma unroll
  for (int m = 0; m < 2; ++m)
#pragma unroll
    for (int r = 0; r < 4; ++r) {
      float s = 0.f;
#pragma unroll
      for (int f = 0; f < NFRAG; ++f) {
        float h = acc[m][f][r] + bv[f];
        h = fmaxf(h, 0.f);
        s = fmaf(h, w2v[f], s);
      }
      part[m][r] = s;
    }

#pragma unroll
  for (int mask = 1; mask < 16; mask <<= 1)
#pragma unroll
    for (int m = 0; m < 2; ++m)
#pragma unroll
      for (int r = 0; r < 4; ++r)
        part[m][r] += __shfl_xor(part[m][r], mask, 64);

  if (l15 == 0) {
#pragma unroll
    for (int m = 0; m < 2; ++m)
#pragma unroll
      for (int r = 0; r < 4; ++r) {
        float x = part[m][r] + bias2;
        out[ebase + m * 16 + kg * 4 + r] = 1.f / (1.f + __expf(-x));
      }
  }
}

extern "C" void kernel_launch(void* const* d_in, const int* in_sizes, int n_in,
                              void* d_out, int out_size, void* d_ws, size_t ws_size,
                              hipStream_t stream) {
  const float* nodef  = (const float*)d_in[0];
  const float* eattr  = (const float*)d_in[1];
  const float* W_edge = (const float*)d_in[2];
  const float* b_edge = (const float*)d_in[3];
  const float* W1     = (const float*)d_in[4];
  const float* b1     = (const float*)d_in[5];
  const float* W2     = (const float*)d_in[6];
  const float* b2     = (const float*)d_in[7];
  const void*  eidx   = d_in[8];

  unsigned short* Bpack    = (unsigned short*)d_ws;
  float*          bias_eff = (float*)((char*)d_ws + BIAS_OFF_BYTES);
  int*            flag64   = (int*)((char*)d_ws + FLAG_OFF_BYTES);
  unsigned short* nbf      = (unsigned short*)((char*)d_ws + NODE_OFF_BYTES);
  int*            idx32    = (int*)((char*)d_ws + IDX_OFF_BYTES);

  setup_kernel<<<dim3(37), dim3(128), 0, stream>>>(W_edge, b_edge, W1, b1, eidx,
                                                   Bpack, bias_eff, flag64);

  if (ws_size >= (size_t)WS_NEEDED) {
    cvt_idx_kernel<<<dim3((2 * NEDGE + 255) / 256), dim3(256), 0, stream>>>(eidx, flag64, idx32);
    cvt_nodes_kernel<<<dim3((NNODE * HIDDEN / 8 + 255) / 256), dim3(256), 0, stream>>>(nodef, nbf);
    edge_attn_kernel<<<dim3(NEDGE / 256), dim3(512), 0, stream>>>(
        nbf, eattr, idx32, Bpack, bias_eff, W2, b2, (float*)d_out);
  } else {
    edge_attn_kernel_fp32<<<dim3(NEDGE / 128), dim3(256), 0, stream>>>(
        nodef, eattr, eidx, Bpack, bias_eff, W2, b2, flag64, (float*)d_out);
  }
}

// Round 10
// 112.898 us; speedup vs baseline: 3.1272x; 1.1406x over previous
//
#include <hip/hip_runtime.h>
#include <hip/hip_bf16.h>

#define HIDDEN   128
#define EDGE_DIM 32
#define NNODE    50000
#define NEDGE    800000
#define KSTEPS   9          // K = 288 = 9*32  (128 src + 128 dst + 32 edge_attr)
#define NFRAG    8          // 128 output cols / 16
#define LDS_KS   8          // K-steps staged in LDS (8*8KB = 65536 B, static max)

typedef __attribute__((ext_vector_type(4))) float        f32x4;
typedef __attribute__((ext_vector_type(8))) short        bf16x8;
typedef __attribute__((ext_vector_type(4))) unsigned int u32x4;

#define BPACK_USHORTS  (KSTEPS * NFRAG * 64 * 8)   // 36864 bf16 = 73728 B
#define BIAS_OFF_BYTES (BPACK_USHORTS * 2)         // 73728
#define FLAG_OFF_BYTES (BIAS_OFF_BYTES + 128 * 4)  // 74240
#define DATA_OFF       74752                       // 16B-aligned

// ---- new-path layout: P/Q packed bf16 (12.8 MB each) + idx32 (6.4 MB)
#define PP_OFF   DATA_OFF
#define QP_OFF   (PP_OFF + NNODE * HIDDEN * 2)
#define IDXN_OFF (QP_OFF + NNODE * HIDDEN * 2)
#define WS_NEW   (IDXN_OFF + 2 * NEDGE * 4)        // ~32.07 MB

// ---- R8-fallback layout: bf16 nodes + idx32
#define NODE_OFF_BYTES DATA_OFF
#define IDX_OFF_BYTES  (NODE_OFF_BYTES + NNODE * HIDDEN * 2)
#define WS_R8          (IDX_OFF_BYTES + 2 * NEDGE * 4)        // ~19.27 MB

__device__ __forceinline__ unsigned short f2bf(float f) {
  unsigned u = __builtin_bit_cast(unsigned, f);
  u += 0x7FFFu + ((u >> 16) & 1u);   // RNE
  return (unsigned short)(u >> 16);
}

__device__ __forceinline__ unsigned cvt_pk_bf16(float a, float b) {
  union { __hip_bfloat162 h; unsigned u; } cv;
  cv.h = __float22bfloat162_rn(make_float2(a, b));   // a -> low 16, b -> high 16
  return cv.u;
}

__device__ __forceinline__ bf16x8 pack8(f32x4 lo, f32x4 hi) {
  u32x4 u;
  u[0] = cvt_pk_bf16(lo[0], lo[1]);
  u[1] = cvt_pk_bf16(lo[2], lo[3]);
  u[2] = cvt_pk_bf16(hi[0], hi[1]);
  u[3] = cvt_pk_bf16(hi[2], hi[3]);
  return __builtin_bit_cast(bf16x8, u);
}

// async global->LDS, 16B per lane
__device__ __forceinline__ void gload_lds16(const void* g, void* l) {
  __builtin_amdgcn_global_load_lds(
      (const __attribute__((address_space(1))) unsigned int*)g,
      (__attribute__((address_space(3))) unsigned int*)l, 16, 0, 0);
}

#define MFMA(a, b, c) __builtin_amdgcn_mfma_f32_16x16x32_bf16((a), (b), (c), 0, 0, 0)

// ---- setup 1: folded, fragment-packed B (bf16) + effective bias + idx dtype flag
__global__ void setup_kernel(const float* __restrict__ W_edge,
                             const float* __restrict__ b_edge,
                             const float* __restrict__ W1,
                             const float* __restrict__ b1,
                             const void*  __restrict__ eidx,
                             unsigned short* __restrict__ Bpack,
                             float* __restrict__ bias_eff,
                             int*   __restrict__ flag64) {
  const int bid = blockIdx.x, tid = threadIdx.x;
  if (bid < 36) {
    const int pair  = bid * 2 + (tid >> 6);   // 0..71 = kstep*8 + nfrag
    const int lane  = tid & 63;
    const int kstep = pair >> 3;
    const int f     = pair & 7;
    const int col   = f * 16 + (lane & 15);
    const int kbase = kstep * 32 + (lane >> 4) * 8;
    float vals[8];
#pragma unroll
    for (int j = 0; j < 8; ++j) {
      const int k = kbase + j;
      float val;
      if (k < 128) {
        val = W1[k * 128 + col];
      } else if (k < 256) {
        val = W1[(k + 128) * 128 + col];
      } else {
        const int kk = k - 256;
        float s = 0.f;
        for (int t = 0; t < 128; ++t)
          s = fmaf(W_edge[kk * 128 + t], W1[(128 + t) * 128 + col], s);
        val = s;
      }
      vals[j] = val;
    }
    u32x4 sv;
#pragma unroll
    for (int j = 0; j < 4; ++j)
      sv[j] = (unsigned)f2bf(vals[2 * j]) | ((unsigned)f2bf(vals[2 * j + 1]) << 16);
    *(u32x4*)(Bpack + ((kstep * NFRAG + f) * 64 + lane) * 8) = sv;
  } else {
    if (tid < 128) {
      float s = b1[tid];
      for (int t = 0; t < 128; ++t)
        s = fmaf(b_edge[t], W1[(128 + t) * 128 + tid], s);
      bias_eff[tid] = s;
    }
    if (tid == 0) {
      const unsigned* w = (const unsigned*)eidx;
      int all0 = 1;
      for (int i = 0; i < 64; ++i) all0 &= (w[2 * i + 1] == 0u) ? 1 : 0;
      *flag64 = all0;
    }
  }
}

// ---- setup 2 (R8 path only): node_features fp32 -> bf16
__global__ __launch_bounds__(256) void cvt_nodes_kernel(const float* __restrict__ nodef,
                                                        unsigned short* __restrict__ nbf) {
  const int i = blockIdx.x * 256 + threadIdx.x;
  if (i >= NNODE * HIDDEN / 8) return;
  f32x4 lo = *(const f32x4*)(nodef + i * 8);
  f32x4 hi = *(const f32x4*)(nodef + i * 8 + 4);
  *(bf16x8*)(nbf + i * 8) = pack8(lo, hi);
}

// ---- setup 3: edge_index (int64 or int32) -> int32
__global__ __launch_bounds__(256) void cvt_idx_kernel(const void* __restrict__ eidx,
                                                      const int* __restrict__ flag64,
                                                      int* __restrict__ idx32) {
  const int i = blockIdx.x * 256 + threadIdx.x;
  if (i >= 2 * NEDGE) return;
  if (*flag64) idx32[i] = (int)((const long long*)eidx)[i];
  else         idx32[i] = ((const int*)eidx)[i];
}

// ---- setup 4 (new path): P = nodef@W1a + b1_eff, Q = nodef@W1c, stored
// packed-bf16: dword d = k*16 + l15 of node n holds feats (32k+l15 | 32k+16+l15).
// 512 thr = 8 waves x 32 nodes = 256 nodes/block; Wa/Wc (Bpack ks0..7) in LDS.
__global__ __launch_bounds__(512, 2) void pq_kernel(
    const float* __restrict__ nodef,
    const unsigned short* __restrict__ Bpack,
    const float* __restrict__ bias_eff,
    unsigned* __restrict__ Pp,
    unsigned* __restrict__ Qp) {
  __shared__ unsigned short lds_b[LDS_KS * NFRAG * 64 * 8];   // 65536 B

  const int tid  = threadIdx.x;
  const int lane = tid & 63;
  const int wid  = tid >> 6;
  const int l15  = lane & 15;
  const int kg   = lane >> 4;
  const int nb   = blockIdx.x * 256 + wid * 32;

#pragma unroll
  for (int i = 0; i < 8; ++i) {
    const char* g = (const char*)Bpack + (size_t)(i * 512 + tid) * 16;
    char*       l = (char*)lds_b + (size_t)(i * 512 + wid * 64) * 16;
    gload_lds16(g, l);
  }

  // A-frags: node rows (A-layout row = l15), fp32 -> bf16
  const int n0 = min(nb + l15, NNODE - 1);
  const int n1 = min(nb + 16 + l15, NNODE - 1);
  bf16x8 a0[4], a1[4];
#pragma unroll
  for (int ks = 0; ks < 4; ++ks) {
    const float* p0 = nodef + (size_t)n0 * HIDDEN + ks * 32 + kg * 8;
    const float* p1 = nodef + (size_t)n1 * HIDDEN + ks * 32 + kg * 8;
    a0[ks] = pack8(*(const f32x4*)p0, *(const f32x4*)(p0 + 4));
    a1[ks] = pack8(*(const f32x4*)p1, *(const f32x4*)(p1 + 4));
  }

  float bv[NFRAG];
#pragma unroll
  for (int f = 0; f < NFRAG; ++f) bv[f] = bias_eff[f * 16 + l15];

  __syncthreads();

  // P pass (W1a = ks 0..3), bias folded into init
  f32x4 acc[2][NFRAG];
#pragma unroll
  for (int m = 0; m < 2; ++m)
#pragma unroll
    for (int f = 0; f < NFRAG; ++f)
      acc[m][f] = (f32x4){bv[f], bv[f], bv[f], bv[f]};
#pragma unroll
  for (int ks = 0; ks < 4; ++ks)
#pragma unroll
    for (int f = 0; f < NFRAG; ++f) {
      bf16x8 bfr = *(const bf16x8*)(lds_b + ((ks * NFRAG + f) * 64 + lane) * 8);
      acc[0][f] = MFMA(a0[ks], bfr, acc[0][f]);
      acc[1][f] = MFMA(a1[ks], bfr, acc[1][f]);
    }
#pragma unroll
  for (int m = 0; m < 2; ++m)
#pragma unroll
    for (int r = 0; r < 4; ++r) {
      const int n = nb + m * 16 + kg * 4 + r;
      if (n < NNODE) {
#pragma unroll
        for (int k = 0; k < 4; ++k)
          Pp[(size_t)n * 64 + k * 16 + l15] =
              cvt_pk_bf16(acc[m][2 * k][r], acc[m][2 * k + 1][r]);
      }
    }

  // Q pass (W1c = ks 4..7), no bias
#pragma unroll
  for (int m = 0; m < 2; ++m)
#pragma unroll
    for (int f = 0; f < NFRAG; ++f)
      acc[m][f] = (f32x4){0.f, 0.f, 0.f, 0.f};
#pragma unroll
  for (int ks = 0; ks < 4; ++ks)
#pragma unroll
    for (int f = 0; f < NFRAG; ++f) {
      bf16x8 bfr = *(const bf16x8*)(lds_b + (((ks + 4) * NFRAG + f) * 64 + lane) * 8);
      acc[0][f] = MFMA(a0[ks], bfr, acc[0][f]);
      acc[1][f] = MFMA(a1[ks], bfr, acc[1][f]);
    }
#pragma unroll
  for (int m = 0; m < 2; ++m)
#pragma unroll
    for (int r = 0; r < 4; ++r) {
      const int n = nb + m * 16 + kg * 4 + r;
      if (n < NNODE) {
#pragma unroll
        for (int k = 0; k < 4; ++k)
          Qp[(size_t)n * 64 + k * 16 + l15] =
              cvt_pk_bf16(acc[m][2 * k][r], acc[m][2 * k + 1][r]);
      }
    }
}

// ---- NEW main: 256 thr = 4 waves x 32 edges = 128 edges/block, grid 6250.
// No LDS, no barriers. E via 16 MFMAs; P/Q gathered in C-layout; fp32 adds.
__global__ __launch_bounds__(256, 3) void edge_attn_pq(
    const float* __restrict__ eattr,
    const int*   __restrict__ idx32,
    const unsigned* __restrict__ Pp,
    const unsigned* __restrict__ Qp,
    const unsigned short* __restrict__ Bpack,
    const float* __restrict__ W2,
    const float* __restrict__ b2,
    float* __restrict__ out) {
  const int tid   = threadIdx.x;
  const int lane  = tid & 63;
  const int wid   = tid >> 6;
  const int l15   = lane & 15;
  const int kg    = lane >> 4;
  const int ebase = blockIdx.x * 128 + wid * 32;

  const f32x4 zero4 = {0.f, 0.f, 0.f, 0.f};

  // node indices for C-layout rows (edge = ebase + m*16 + kg*4 + r)
  int rn[2][4], cn[2][4];
#pragma unroll
  for (int m = 0; m < 2; ++m)
#pragma unroll
    for (int r = 0; r < 4; ++r) {
      rn[m][r] = idx32[ebase + m * 16 + kg * 4 + r];
      cn[m][r] = idx32[NEDGE + ebase + m * 16 + kg * 4 + r];
    }

  // eattr A-frags (A-layout row = l15, k = kg*8+j)
  bf16x8 ae0, ae1;
  {
    const float* pe = eattr + (size_t)(ebase + l15) * EDGE_DIM + kg * 8;
    ae0 = pack8(*(const f32x4*)pe, *(const f32x4*)(pe + 4));
  }
  {
    const float* pe = eattr + (size_t)(ebase + 16 + l15) * EDGE_DIM + kg * 8;
    ae1 = pack8(*(const f32x4*)pe, *(const f32x4*)(pe + 4));
  }

  // E = eattr @ Wfold (Bpack kstep 8), acc in C-layout
  f32x4 acc[2][NFRAG];
#pragma unroll
  for (int f = 0; f < NFRAG; ++f) {
    bf16x8 bfr = *(const bf16x8*)(Bpack + ((8 * NFRAG + f) * 64 + lane) * 8);
    acc[0][f] = MFMA(ae0, bfr, zero4);
    acc[1][f] = MFMA(ae1, bfr, zero4);
  }

  // gather P[row], Q[col] (packed bf16, L2/L3-resident)
  unsigned pu[2][4][4], qu[2][4][4];
#pragma unroll
  for (int m = 0; m < 2; ++m)
#pragma unroll
    for (int r = 0; r < 4; ++r) {
      const unsigned* pb = Pp + (size_t)rn[m][r] * 64 + l15;
      const unsigned* qb = Qp + (size_t)cn[m][r] * 64 + l15;
#pragma unroll
      for (int k = 0; k < 4; ++k) {
        pu[m][r][k] = pb[k * 16];
        qu[m][r][k] = qb[k * 16];
      }
    }

  // accumulate: bf16 lo/hi -> f32 via bit ops
#pragma unroll
  for (int m = 0; m < 2; ++m)
#pragma unroll
    for (int r = 0; r < 4; ++r)
#pragma unroll
      for (int k = 0; k < 4; ++k) {
        const unsigned up = pu[m][r][k], uq = qu[m][r][k];
        acc[m][2 * k][r]     += __builtin_bit_cast(float, up << 16)
                              + __builtin_bit_cast(float, uq << 16);
        acc[m][2 * k + 1][r] += __builtin_bit_cast(float, up & 0xffff0000u)
                              + __builtin_bit_cast(float, uq & 0xffff0000u);
      }

  // epilogue: relu + dot(W2) (b1 already in P), 16-lane xor-reduce, sigmoid
  float w2v[NFRAG];
#pragma unroll
  for (int f = 0; f < NFRAG; ++f) w2v[f] = W2[f * 16 + l15];
  const float bias2 = b2[0];

  float part[2][4];
#pragma unroll
  for (int m = 0; m < 2; ++m)
#pragma unroll
    for (int rr = 0; rr < 4; ++rr) {
      float s = 0.f;
#pragma unroll
      for (int f = 0; f < NFRAG; ++f) {
        float h = fmaxf(acc[m][f][rr], 0.f);
        s = fmaf(h, w2v[f], s);
      }
      part[m][rr] = s;
    }

#pragma unroll
  for (int mask = 1; mask < 16; mask <<= 1)
#pragma unroll
    for (int m = 0; m < 2; ++m)
#pragma unroll
      for (int rr = 0; rr < 4; ++rr)
        part[m][rr] += __shfl_xor(part[m][rr], mask, 64);

  if (l15 == 0) {
#pragma unroll
    for (int m = 0; m < 2; ++m)
#pragma unroll
      for (int rr = 0; rr < 4; ++rr) {
        float x = part[m][rr] + bias2;
        out[ebase + m * 16 + kg * 4 + rr] = 1.f / (1.f + __expf(-x));
      }
  }
}

// ---- R8 fallback main (bf16 nodes, LDS-staged B)
__global__ __launch_bounds__(512, 4) void edge_attn_kernel(
    const unsigned short* __restrict__ nbf,
    const float* __restrict__ eattr,
    const int*   __restrict__ idx32,
    const unsigned short* __restrict__ Bpack,
    const float* __restrict__ bias_eff,
    const float* __restrict__ W2,
    const float* __restrict__ b2,
    float* __restrict__ out) {
  __shared__ unsigned short lds_b[LDS_KS * NFRAG * 64 * 8];

  const int tid   = threadIdx.x;
  const int lane  = tid & 63;
  const int wid   = tid >> 6;
  const int l15   = lane & 15;
  const int kg    = lane >> 4;
  const int ebase = blockIdx.x * 256 + wid * 32;

#pragma unroll
  for (int i = 0; i < 8; ++i) {
    const char* g = (const char*)Bpack + (size_t)(i * 512 + tid) * 16;
    char*       l = (char*)lds_b + (size_t)(i * 512 + wid * 64) * 16;
    gload_lds16(g, l);
  }

  const int r0 = idx32[ebase + l15];
  const int r1 = idx32[ebase + 16 + l15];
  const int c0 = idx32[NEDGE + ebase + l15];
  const int c1 = idx32[NEDGE + ebase + 16 + l15];

  bf16x8 a0[4], a1[4];
#pragma unroll
  for (int ks = 0; ks < 4; ++ks) {
    a0[ks] = *(const bf16x8*)(nbf + (size_t)r0 * HIDDEN + kg * 8 + ks * 32);
    a1[ks] = *(const bf16x8*)(nbf + (size_t)r1 * HIDDEN + kg * 8 + ks * 32);
  }

  __syncthreads();

  f32x4 acc[2][NFRAG];
#pragma unroll
  for (int m = 0; m < 2; ++m)
#pragma unroll
    for (int f = 0; f < NFRAG; ++f)
      acc[m][f] = (f32x4){0.f, 0.f, 0.f, 0.f};

#pragma unroll
  for (int ks = 0; ks < 4; ++ks)
#pragma unroll
    for (int f = 0; f < NFRAG; ++f) {
      bf16x8 bfr = *(const bf16x8*)(lds_b + ((ks * NFRAG + f) * 64 + lane) * 8);
      acc[0][f] = MFMA(a0[ks], bfr, acc[0][f]);
      acc[1][f] = MFMA(a1[ks], bfr, acc[1][f]);
    }

  __builtin_amdgcn_sched_barrier(0);

#pragma unroll
  for (int ks = 0; ks < 4; ++ks) {
    a0[ks] = *(const bf16x8*)(nbf + (size_t)c0 * HIDDEN + kg * 8 + ks * 32);
    a1[ks] = *(const bf16x8*)(nbf + (size_t)c1 * HIDDEN + kg * 8 + ks * 32);
  }

#pragma unroll
  for (int ks = 0; ks < 4; ++ks)
#pragma unroll
    for (int f = 0; f < NFRAG; ++f) {
      bf16x8 bfr = *(const bf16x8*)(lds_b + (((ks + 4) * NFRAG + f) * 64 + lane) * 8);
      acc[0][f] = MFMA(a0[ks], bfr, acc[0][f]);
      acc[1][f] = MFMA(a1[ks], bfr, acc[1][f]);
    }

  __builtin_amdgcn_sched_barrier(0);

  bf16x8 ae0, ae1;
  {
    const float* pe = eattr + (size_t)(ebase + l15) * EDGE_DIM + kg * 8;
    ae0 = pack8(*(const f32x4*)pe, *(const f32x4*)(pe + 4));
  }
  {
    const float* pe = eattr + (size_t)(ebase + 16 + l15) * EDGE_DIM + kg * 8;
    ae1 = pack8(*(const f32x4*)pe, *(const f32x4*)(pe + 4));
  }
#pragma unroll
  for (int f = 0; f < NFRAG; ++f) {
    bf16x8 bfr = *(const bf16x8*)(Bpack + ((8 * NFRAG + f) * 64 + lane) * 8);
    acc[0][f] = MFMA(ae0, bfr, acc[0][f]);
    acc[1][f] = MFMA(ae1, bfr, acc[1][f]);
  }

  float w2v[NFRAG], bv[NFRAG];
#pragma unroll
  for (int f = 0; f < NFRAG; ++f) {
    w2v[f] = W2[f * 16 + l15];
    bv[f]  = bias_eff[f * 16 + l15];
  }
  const float bias2 = b2[0];

  float part[2][4];
#pragma unroll
  for (int m = 0; m < 2; ++m)
#pragma unroll
    for (int rr = 0; rr < 4; ++rr) {
      float s = 0.f;
#pragma unroll
      for (int f = 0; f < NFRAG; ++f) {
        float h = fmaxf(acc[m][f][rr] + bv[f], 0.f);
        s = fmaf(h, w2v[f], s);
      }
      part[m][rr] = s;
    }

#pragma unroll
  for (int mask = 1; mask < 16; mask <<= 1)
#pragma unroll
    for (int m = 0; m < 2; ++m)
#pragma unroll
      for (int rr = 0; rr < 4; ++rr)
        part[m][rr] += __shfl_xor(part[m][rr], mask, 64);

  if (l15 == 0) {
#pragma unroll
    for (int m = 0; m < 2; ++m)
#pragma unroll
      for (int rr = 0; rr < 4; ++rr) {
        float x = part[m][rr] + bias2;
        out[ebase + m * 16 + kg * 4 + rr] = 1.f / (1.f + __expf(-x));
      }
  }
}

// ---- last-resort fallback (fp32 gathers, global B)
__global__ __launch_bounds__(256) void edge_attn_kernel_fp32(
    const float* __restrict__ nodef,
    const float* __restrict__ eattr,
    const void*  __restrict__ eidx,
    const unsigned short* __restrict__ Bpack,
    const float* __restrict__ bias_eff,
    const float* __restrict__ W2,
    const float* __restrict__ b2,
    const int*   __restrict__ flag64,
    float* __restrict__ out) {
  const int lane  = threadIdx.x & 63;
  const int wid   = threadIdx.x >> 6;
  const int ebase = blockIdx.x * 128 + wid * 32;
  const int l15   = lane & 15;
  const int kg    = lane >> 4;
  const int koff  = kg * 8;
  const int e0 = ebase + l15;
  const int e1 = e0 + 16;

  long r0, c0, r1, c1;
  if (*flag64) {
    const long long* p = (const long long*)eidx;
    r0 = (long)p[e0];          r1 = (long)p[e1];
    c0 = (long)p[NEDGE + e0];  c1 = (long)p[NEDGE + e1];
  } else {
    const int* p = (const int*)eidx;
    r0 = p[e0];          r1 = p[e1];
    c0 = p[NEDGE + e0];  c1 = p[NEDGE + e1];
  }

  f32x4 acc[2][NFRAG];
#pragma unroll
  for (int m = 0; m < 2; ++m)
#pragma unroll
    for (int f = 0; f < NFRAG; ++f)
      acc[m][f] = (f32x4){0.f, 0.f, 0.f, 0.f};

#pragma unroll 1
  for (int ks = 0; ks < KSTEPS; ++ks) {
    const float *p0, *p1;
    if (ks < 4)      { p0 = nodef + r0 * HIDDEN + ks * 32;       p1 = nodef + r1 * HIDDEN + ks * 32; }
    else if (ks < 8) { p0 = nodef + c0 * HIDDEN + (ks - 4) * 32; p1 = nodef + c1 * HIDDEN + (ks - 4) * 32; }
    else             { p0 = eattr + (long)e0 * EDGE_DIM;         p1 = eattr + (long)e1 * EDGE_DIM; }

    f32x4 lo0 = *(const f32x4*)(p0 + koff);
    f32x4 hi0 = *(const f32x4*)(p0 + koff + 4);
    f32x4 lo1 = *(const f32x4*)(p1 + koff);
    f32x4 hi1 = *(const f32x4*)(p1 + koff + 4);
    bf16x8 a0 = pack8(lo0, hi0);
    bf16x8 a1 = pack8(lo1, hi1);

#pragma unroll
    for (int f = 0; f < NFRAG; ++f) {
      bf16x8 bfr = *(const bf16x8*)(Bpack + ((ks * NFRAG + f) * 64 + lane) * 8);
      acc[0][f] = MFMA(a0, bfr, acc[0][f]);
      acc[1][f] = MFMA(a1, bfr, acc[1][f]);
    }
  }

  float w2v[NFRAG], bv[NFRAG];
#pragma unroll
  for (int f = 0; f < NFRAG; ++f) {
    w2v[f] = W2[f * 16 + l15];
    bv[f]  = bias_eff[f * 16 + l15];
  }
  const float bias2 = b2[0];

  float part[2][4];
#pragma unroll
  for (int m = 0; m < 2; ++m)
#pragma unroll
    for (int r = 0; r < 4; ++r) {
      float s = 0.f;
#pragma unroll
      for (int f = 0; f < NFRAG; ++f) {
        float h = acc[m][f][r] + bv[f];
        h = fmaxf(h, 0.f);
        s = fmaf(h, w2v[f], s);
      }
      part[m][r] = s;
    }

#pragma unroll
  for (int mask = 1; mask < 16; mask <<= 1)
#pragma unroll
    for (int m = 0; m < 2; ++m)
#pragma unroll
      for (int r = 0; r < 4; ++r)
        part[m][r] += __shfl_xor(part[m][r], mask, 64);

  if (l15 == 0) {
#pragma unroll
    for (int m = 0; m < 2; ++m)
#pragma unroll
      for (int r = 0; r < 4; ++r) {
        float x = part[m][r] + bias2;
        out[ebase + m * 16 + kg * 4 + r] = 1.f / (1.f + __expf(-x));
      }
  }
}

extern "C" void kernel_launch(void* const* d_in, const int* in_sizes, int n_in,
                              void* d_out, int out_size, void* d_ws, size_t ws_size,
                              hipStream_t stream) {
  const float* nodef  = (const float*)d_in[0];
  const float* eattr  = (const float*)d_in[1];
  const float* W_edge = (const float*)d_in[2];
  const float* b_edge = (const float*)d_in[3];
  const float* W1     = (const float*)d_in[4];
  const float* b1     = (const float*)d_in[5];
  const float* W2     = (const float*)d_in[6];
  const float* b2     = (const float*)d_in[7];
  const void*  eidx   = d_in[8];

  unsigned short* Bpack    = (unsigned short*)d_ws;
  float*          bias_eff = (float*)((char*)d_ws + BIAS_OFF_BYTES);
  int*            flag64   = (int*)((char*)d_ws + FLAG_OFF_BYTES);

  setup_kernel<<<dim3(37), dim3(128), 0, stream>>>(W_edge, b_edge, W1, b1, eidx,
                                                   Bpack, bias_eff, flag64);

  if (ws_size >= (size_t)WS_NEW) {
    unsigned* Pp    = (unsigned*)((char*)d_ws + PP_OFF);
    unsigned* Qp    = (unsigned*)((char*)d_ws + QP_OFF);
    int*      idx32 = (int*)((char*)d_ws + IDXN_OFF);
    cvt_idx_kernel<<<dim3((2 * NEDGE + 255) / 256), dim3(256), 0, stream>>>(eidx, flag64, idx32);
    pq_kernel<<<dim3((NNODE + 255) / 256), dim3(512), 0, stream>>>(nodef, Bpack, bias_eff, Pp, Qp);
    edge_attn_pq<<<dim3(NEDGE / 128), dim3(256), 0, stream>>>(
        eattr, idx32, Pp, Qp, Bpack, W2, b2, (float*)d_out);
  } else if (ws_size >= (size_t)WS_R8) {
    unsigned short* nbf   = (unsigned short*)((char*)d_ws + NODE_OFF_BYTES);
    int*            idx32 = (int*)((char*)d_ws + IDX_OFF_BYTES);
    cvt_idx_kernel<<<dim3((2 * NEDGE + 255) / 256), dim3(256), 0, stream>>>(eidx, flag64, idx32);
    cvt_nodes_kernel<<<dim3((NNODE * HIDDEN / 8 + 255) / 256), dim3(256), 0, stream>>>(nodef, nbf);
    edge_attn_kernel<<<dim3(NEDGE / 256), dim3(512), 0, stream>>>(
        nbf, eattr, idx32, Bpack, bias_eff, W2, b2, (float*)d_out);
  } else {
    edge_attn_kernel_fp32<<<dim3(NEDGE / 128), dim3(256), 0, stream>>>(
        nodef, eattr, eidx, Bpack, bias_eff, W2, b2, flag64, (float*)d_out);
  }
}